// Round 1
// baseline (7380.430 us; speedup 1.0000x reference)
//
#include <hip/hip_runtime.h>
#include <math.h>

#define NN 20000
#define NE 200000
#define HH 512

// ---------------- GEMM: out[M,512] = X[M,K] @ W[K,512] + b ----------------
// 128x64 block tile, 256 threads, 8x4 per thread, K-step 16.
__global__ __launch_bounds__(256)
void lin_kernel(const float* __restrict__ X, const float* __restrict__ W,
                const float* __restrict__ bias, float* __restrict__ out,
                int M, int K)
{
    __shared__ float XsT[16][132];   // [k][row], pad 132 (16B-aligned rows, bank-spread)
    __shared__ float Ws[16][68];     // [k][col]
    const int tid = threadIdx.x;
    const int tx = tid & 15, ty = tid >> 4;
    const int row0 = blockIdx.y * 128;
    const int col0 = blockIdx.x * 64;

    const int lr = tid >> 1;          // 0..127 : X row to load
    const int lc = (tid & 1) * 8;     // 0 or 8 : k-offset
    const int gr_load = row0 + lr;
    const int wr = tid >> 4;          // 0..15  : W k-row
    const int wc = (tid & 15) * 4;    // 0..60  : W col

    float acc[8][4];
#pragma unroll
    for (int i = 0; i < 8; ++i)
#pragma unroll
        for (int j = 0; j < 4; ++j) acc[i][j] = 0.f;

    for (int kk = 0; kk < K; kk += 16) {
        float4 v0 = make_float4(0.f,0.f,0.f,0.f), v1 = v0;
        if (gr_load < M) {
            const float* xp = X + (size_t)gr_load * K + kk + lc;
            v0 = *(const float4*)xp;
            v1 = *(const float4*)(xp + 4);
        }
        float4 w4 = *(const float4*)(W + (size_t)(kk + wr) * HH + col0 + wc);
        __syncthreads();
        XsT[lc+0][lr] = v0.x; XsT[lc+1][lr] = v0.y; XsT[lc+2][lr] = v0.z; XsT[lc+3][lr] = v0.w;
        XsT[lc+4][lr] = v1.x; XsT[lc+5][lr] = v1.y; XsT[lc+6][lr] = v1.z; XsT[lc+7][lr] = v1.w;
        *(float4*)&Ws[wr][wc] = w4;
        __syncthreads();
#pragma unroll
        for (int k = 0; k < 16; ++k) {
            float a[8], w[4];
            *(float4*)&a[0] = *(const float4*)&XsT[k][ty*8];
            *(float4*)&a[4] = *(const float4*)&XsT[k][ty*8+4];
            *(float4*)&w[0] = *(const float4*)&Ws[k][tx*4];
#pragma unroll
            for (int i = 0; i < 8; ++i)
#pragma unroll
                for (int j = 0; j < 4; ++j)
                    acc[i][j] = fmaf(a[i], w[j], acc[i][j]);
        }
    }
    float4 bv = *(const float4*)(bias + col0 + tx*4);
#pragma unroll
    for (int i = 0; i < 8; ++i) {
        int gr = row0 + ty*8 + i;
        if (gr < M) {
            float4 o;
            o.x = acc[i][0] + bv.x; o.y = acc[i][1] + bv.y;
            o.z = acc[i][2] + bv.z; o.w = acc[i][3] + bv.w;
            *(float4*)(out + (size_t)gr * HH + col0 + tx*4) = o;
        }
    }
}

// ---------------- per-row double dot: ss = S.aw[0:512], ts = T.aw[512:1024] --
__global__ __launch_bounds__(256)
void rowdot_kernel(const float* __restrict__ S, const float* __restrict__ T,
                   const float* __restrict__ aw, float* __restrict__ ss,
                   float* __restrict__ ts, int N)
{
    int row = blockIdx.x * 4 + (threadIdx.x >> 6);
    int lane = threadIdx.x & 63;
    if (row >= N) return;
    const float4* sp = (const float4*)(S + (size_t)row * HH);
    const float4* tp = (const float4*)(T + (size_t)row * HH);
    const float4* ah = (const float4*)aw;
    const float4* at = (const float4*)(aw + HH);
    float accs = 0.f, acct = 0.f;
#pragma unroll
    for (int l = 0; l < 2; ++l) {
        int idx = lane * 2 + l;
        float4 sv = sp[idx], av = ah[idx];
        accs += sv.x*av.x + sv.y*av.y + sv.z*av.z + sv.w*av.w;
        float4 tv = tp[idx], bv = at[idx];
        acct += tv.x*bv.x + tv.y*bv.y + tv.z*bv.z + tv.w*bv.w;
    }
#pragma unroll
    for (int m = 32; m >= 1; m >>= 1) {
        accs += __shfl_xor(accs, m);
        acct += __shfl_xor(acct, m);
    }
    if (lane == 0) { ss[row] = accs; ts[row] = acct; }
}

// ---------------- edge pass 1: w = exp(tanh(ss[src]+ts[tgt]+ab)); den[src]+=w
__global__ __launch_bounds__(256)
void edge_w_kernel(const int* __restrict__ src, const int* __restrict__ tgt,
                   const float* __restrict__ ss, const float* __restrict__ ts,
                   const float* __restrict__ ab_ptr, float* __restrict__ wbuf,
                   float* __restrict__ den, int E)
{
    int i = blockIdx.x * blockDim.x + threadIdx.x;
    if (i >= E) return;
    int s = src[i], t = tgt[i];
    float e = tanhf(ss[s] + ts[t] + ab_ptr[0]);
    float w = expf(e);
    wbuf[i] = w;
    unsafeAtomicAdd(&den[s], w);
}

// ---------------- edge pass 2: hp[src,:] += (w/den[src]) * T[tgt,:] ----------
__global__ __launch_bounds__(256)
void edge_scatter_kernel(const int* __restrict__ src, const int* __restrict__ tgt,
                         const float* __restrict__ wbuf, const float* __restrict__ den,
                         const float* __restrict__ T, float* __restrict__ hp, int E)
{
    int e = blockIdx.x * 4 + (threadIdx.x >> 6);
    int lane = threadIdx.x & 63;
    if (e >= E) return;
    int s = src[e], t = tgt[e];
    float alpha = wbuf[e] / den[s];
    const float4* tp = (const float4*)(T + (size_t)t * HH);
    float* hq = hp + (size_t)s * HH;
#pragma unroll
    for (int l = 0; l < 2; ++l) {
        int idx = lane * 2 + l;
        float4 v = tp[idx];
        unsafeAtomicAdd(hq + idx*4 + 0, alpha * v.x);
        unsafeAtomicAdd(hq + idx*4 + 1, alpha * v.y);
        unsafeAtomicAdd(hq + idx*4 + 2, alpha * v.z);
        unsafeAtomicAdd(hq + idx*4 + 3, alpha * v.w);
    }
}

// ---------------- out = (A + Hp + bias) * 0.5 (elementwise, bias per col) ----
__global__ __launch_bounds__(256)
void combine_kernel(const float* __restrict__ A, const float* __restrict__ Hp,
                    const float* __restrict__ bias, float* __restrict__ out, int n4)
{
    int i = blockIdx.x * blockDim.x + threadIdx.x;
    if (i >= n4) return;
    float4 a = ((const float4*)A)[i];
    float4 h = ((const float4*)Hp)[i];
    float4 b = ((const float4*)bias)[i & 127];
    float4 o;
    o.x = (a.x + h.x + b.x) * 0.5f;
    o.y = (a.y + h.y + b.y) * 0.5f;
    o.z = (a.z + h.z + b.z) * 0.5f;
    o.w = (a.w + h.w + b.w) * 0.5f;
    ((float4*)out)[i] = o;
}

// ---------------- out = LN(tanh(Z [+ res])) * g + b, row-wise (H=512) -------
__global__ __launch_bounds__(256)
void tanh_ln_kernel(const float* __restrict__ Z, const float* __restrict__ res,
                    const float* __restrict__ g, const float* __restrict__ bta,
                    float* __restrict__ out, int N)
{
    int row = blockIdx.x * 4 + (threadIdx.x >> 6);
    int lane = threadIdx.x & 63;
    if (row >= N) return;
    const float4* zp = (const float4*)(Z + (size_t)row * HH);
    float v[8];
    float sum = 0.f, sum2 = 0.f;
#pragma unroll
    for (int l = 0; l < 2; ++l) {
        int idx = lane * 2 + l;
        float4 z = zp[idx];
        if (res) {
            float4 r = ((const float4*)(res + (size_t)row * HH))[idx];
            z.x += r.x; z.y += r.y; z.z += r.z; z.w += r.w;
        }
        float t0 = tanhf(z.x), t1 = tanhf(z.y), t2 = tanhf(z.z), t3 = tanhf(z.w);
        v[l*4+0] = t0; v[l*4+1] = t1; v[l*4+2] = t2; v[l*4+3] = t3;
        sum  += t0 + t1 + t2 + t3;
        sum2 += t0*t0 + t1*t1 + t2*t2 + t3*t3;
    }
#pragma unroll
    for (int m = 32; m >= 1; m >>= 1) {
        sum  += __shfl_xor(sum, m);
        sum2 += __shfl_xor(sum2, m);
    }
    float mu  = sum * (1.f/HH);
    float var = sum2 * (1.f/HH) - mu*mu;
    float rs  = rsqrtf(var + 1e-5f);
#pragma unroll
    for (int l = 0; l < 2; ++l) {
        int idx = lane * 2 + l;
        float4 gv = ((const float4*)g)[idx];
        float4 bv = ((const float4*)bta)[idx];
        float4 o;
        o.x = (v[l*4+0]-mu)*rs*gv.x + bv.x;
        o.y = (v[l*4+1]-mu)*rs*gv.y + bv.y;
        o.z = (v[l*4+2]-mu)*rs*gv.z + bv.z;
        o.w = (v[l*4+3]-mu)*rs*gv.w + bv.w;
        ((float4*)(out + (size_t)row * HH))[idx] = o;
    }
}

// ---------------- out[n] = sigmoid(X[n,:].Wc + bc) ---------------------------
__global__ __launch_bounds__(256)
void cls_kernel(const float* __restrict__ X, const float* __restrict__ Wc,
                const float* __restrict__ bc, float* __restrict__ out, int N)
{
    int row = blockIdx.x * 4 + (threadIdx.x >> 6);
    int lane = threadIdx.x & 63;
    if (row >= N) return;
    const float4* xp = (const float4*)(X + (size_t)row * HH);
    const float4* wp = (const float4*)Wc;
    float acc = 0.f;
#pragma unroll
    for (int l = 0; l < 2; ++l) {
        int idx = lane * 2 + l;
        float4 x = xp[idx], w = wp[idx];
        acc += x.x*w.x + x.y*w.y + x.z*w.z + x.w*w.w;
    }
#pragma unroll
    for (int m = 32; m >= 1; m >>= 1) acc += __shfl_xor(acc, m);
    if (lane == 0) out[row] = 1.f / (1.f + expf(-(acc + bc[0])));
}

extern "C" void kernel_launch(void* const* d_in, const int* in_sizes, int n_in,
                              void* d_out, int out_size, void* d_ws, size_t ws_size,
                              hipStream_t stream)
{
    (void)in_sizes; (void)n_in; (void)out_size; (void)ws_size;
    const int N = NN, E = NE, H = HH;
    const size_t NHf = (size_t)N * H;

    const float* fu0 = (const float*)d_in[0];
    // d_in[1] feat_item_h0 : dead in reference
    // d_in[2] feat_user_h1 : dead (hop-1 su_new never consumed)
    const float* fi1 = (const float*)d_in[3];
    const float* fu2 = (const float*)d_in[4];
    // d_in[5] feat_item_h2 : dead (only fed hop-1 GAT0 which is dead)
    const int* eUI0 = (const int*)d_in[6];
    // d_in[7] edges_IU_h0 : dead
    // d_in[8] edges_UI_h1 : dead
    const int* eIU1 = (const int*)d_in[9];
    const float* Wu  = (const float*)d_in[10];
    const float* bu  = (const float*)d_in[11];
    const float* Wi  = (const float*)d_in[12];
    const float* bi  = (const float*)d_in[13];
    const float* gfW = (const float*)d_in[14];
    const float* gfb = (const float*)d_in[15];
    const float* gaw = (const float*)d_in[16];
    const float* gab = (const float*)d_in[17];
    const float* gbias = (const float*)d_in[18];
    const float* prW = (const float*)d_in[19];
    const float* prb = (const float*)d_in[20];
    const float* dW  = (const float*)d_in[21];
    const float* db  = (const float*)d_in[22];
    const float* dlg = (const float*)d_in[23];
    const float* dlb = (const float*)d_in[24];
    const float* rlg = (const float*)d_in[25];
    const float* rlb = (const float*)d_in[26];
    const float* cW  = (const float*)d_in[27];
    const float* cb  = (const float*)d_in[28];

    float* B0 = (float*)d_ws;        // su (h2) -> later su_final
    float* B1 = B0 + NHf;            // hi (h1) -> si_new (in place)
    float* B2 = B1 + NHf;            // hu0 / x
    float* B3 = B2 + NHf;            // s scratch / dnn gemm out
    float* B4 = B3 + NHf;            // t scratch
    float* B5 = B4 + NHf;            // hp scatter target
    float* wbuf = B5 + NHf;          // [E]
    float* den  = wbuf + E;          // [N]
    float* ssb  = den + N;           // [N]
    float* tsb  = ssb + N;           // [N]

    dim3 gblk(256);
    dim3 ggrd(8, (N + 127) / 128);
    auto LIN = [&](const float* X, const float* W, const float* b, float* o, int K) {
        hipLaunchKernelGGL(lin_kernel, ggrd, gblk, 0, stream, X, W, b, o, N, K);
    };
    const int rgrid = (N + 3) / 4;
    const int egrid_t = (E + 255) / 256;
    const int egrid_w = (E + 3) / 4;
    const int n4 = (int)(NHf / 4);
    const int cgrid = (n4 + 255) / 256;

    auto GAT = [&](int r, const float* head, const float* tail, const int* edges, float* hp) {
        LIN(head, gfW + (size_t)r*H*H, gfb + r*H, B3, H);
        LIN(tail, gfW + (size_t)r*H*H, gfb + r*H, B4, H);
        hipLaunchKernelGGL(rowdot_kernel, dim3(rgrid), dim3(256), 0, stream,
                           B3, B4, gaw + r*2*H, ssb, tsb, N);
        hipMemsetAsync(den, 0, N*sizeof(float), stream);
        hipMemsetAsync(hp, 0, NHf*sizeof(float), stream);
        hipLaunchKernelGGL(edge_w_kernel, dim3(egrid_t), dim3(256), 0, stream,
                           edges, edges + E, ssb, tsb, gab + r, wbuf, den, E);
        hipLaunchKernelGGL(edge_scatter_kernel, dim3(egrid_w), dim3(256), 0, stream,
                           edges, edges + E, wbuf, den, B4, hp, E);
    };

    // hop-2 / hop-1 live transforms
    LIN(fu2, Wu, bu, B0, 512);       // su  = user_h2 transform
    LIN(fi1, Wi, bi, B1, 256);       // hi  = item_h1 transform
    // si_new = (hi + GAT1(hi, su)) * 0.5
    GAT(1, B1, B0, eIU1, B5);
    hipLaunchKernelGGL(combine_kernel, dim3(cgrid), dim3(256), 0, stream,
                       B1, B5, gbias + H, B1, n4);
    // hop 0: su_final = (hu0 + GAT0(hu0, si_new)) * 0.5
    LIN(fu0, Wu, bu, B2, 512);       // hu0
    GAT(0, B2, B1, eUI0, B5);
    hipLaunchKernelGGL(combine_kernel, dim3(cgrid), dim3(256), 0, stream,
                       B2, B5, gbias + 0, B0, n4);

    // Res_DNN head
    LIN(B0, prW, prb, B2, 512);      // x in B2
    for (int r = 0; r < 2; ++r) {
        hipMemcpyAsync(B1, B2, NHf*sizeof(float), hipMemcpyDeviceToDevice, stream); // sc
        for (int d = 0; d < 2; ++d) {
            LIN(B2, dW + ((size_t)(r*2+d))*H*H, db + (r*2+d)*H, B3, 512);
            hipLaunchKernelGGL(tanh_ln_kernel, dim3(rgrid), dim3(256), 0, stream,
                               B3, (const float*)nullptr, dlg + (r*2+d)*H, dlb + (r*2+d)*H, B2, N);
        }
        hipLaunchKernelGGL(tanh_ln_kernel, dim3(rgrid), dim3(256), 0, stream,
                           B2, B1, rlg + r*H, rlb + r*H, B2, N);
    }
    hipLaunchKernelGGL(cls_kernel, dim3(rgrid), dim3(256), 0, stream,
                       B2, cW, cb, (float*)d_out, N);
}

// Round 2
// 2115.250 us; speedup vs baseline: 3.4892x; 3.4892x over previous
//
#include <hip/hip_runtime.h>
#include <math.h>

#define NN 20000
#define NE 200000
#define HH 512

// ---------------- GEMM: out[M,512] = X[M,K] @ W[K,512] + b ----------------
// 128x64 block tile, 256 threads, 8x4 per thread, K-step 16.
__global__ __launch_bounds__(256)
void lin_kernel(const float* __restrict__ X, const float* __restrict__ W,
                const float* __restrict__ bias, float* __restrict__ out,
                int M, int K)
{
    __shared__ float XsT[16][132];
    __shared__ float Ws[16][68];
    const int tid = threadIdx.x;
    const int tx = tid & 15, ty = tid >> 4;
    const int row0 = blockIdx.y * 128;
    const int col0 = blockIdx.x * 64;

    const int lr = tid >> 1;
    const int lc = (tid & 1) * 8;
    const int gr_load = row0 + lr;
    const int wr = tid >> 4;
    const int wc = (tid & 15) * 4;

    float acc[8][4];
#pragma unroll
    for (int i = 0; i < 8; ++i)
#pragma unroll
        for (int j = 0; j < 4; ++j) acc[i][j] = 0.f;

    for (int kk = 0; kk < K; kk += 16) {
        float4 v0 = make_float4(0.f,0.f,0.f,0.f), v1 = v0;
        if (gr_load < M) {
            const float* xp = X + (size_t)gr_load * K + kk + lc;
            v0 = *(const float4*)xp;
            v1 = *(const float4*)(xp + 4);
        }
        float4 w4 = *(const float4*)(W + (size_t)(kk + wr) * HH + col0 + wc);
        __syncthreads();
        XsT[lc+0][lr] = v0.x; XsT[lc+1][lr] = v0.y; XsT[lc+2][lr] = v0.z; XsT[lc+3][lr] = v0.w;
        XsT[lc+4][lr] = v1.x; XsT[lc+5][lr] = v1.y; XsT[lc+6][lr] = v1.z; XsT[lc+7][lr] = v1.w;
        *(float4*)&Ws[wr][wc] = w4;
        __syncthreads();
#pragma unroll
        for (int k = 0; k < 16; ++k) {
            float a[8], w[4];
            *(float4*)&a[0] = *(const float4*)&XsT[k][ty*8];
            *(float4*)&a[4] = *(const float4*)&XsT[k][ty*8+4];
            *(float4*)&w[0] = *(const float4*)&Ws[k][tx*4];
#pragma unroll
            for (int i = 0; i < 8; ++i)
#pragma unroll
                for (int j = 0; j < 4; ++j)
                    acc[i][j] = fmaf(a[i], w[j], acc[i][j]);
        }
    }
    float4 bv = *(const float4*)(bias + col0 + tx*4);
#pragma unroll
    for (int i = 0; i < 8; ++i) {
        int gr = row0 + ty*8 + i;
        if (gr < M) {
            float4 o;
            o.x = acc[i][0] + bv.x; o.y = acc[i][1] + bv.y;
            o.z = acc[i][2] + bv.z; o.w = acc[i][3] + bv.w;
            *(float4*)(out + (size_t)gr * HH + col0 + tx*4) = o;
        }
    }
}

// ---------------- per-row double dot: ss = S.aw[0:512], ts = T.aw[512:1024] --
__global__ __launch_bounds__(256)
void rowdot_kernel(const float* __restrict__ S, const float* __restrict__ T,
                   const float* __restrict__ aw, float* __restrict__ ss,
                   float* __restrict__ ts, int N)
{
    int row = blockIdx.x * 4 + (threadIdx.x >> 6);
    int lane = threadIdx.x & 63;
    if (row >= N) return;
    const float4* sp = (const float4*)(S + (size_t)row * HH);
    const float4* tp = (const float4*)(T + (size_t)row * HH);
    const float4* ah = (const float4*)aw;
    const float4* at = (const float4*)(aw + HH);
    float accs = 0.f, acct = 0.f;
#pragma unroll
    for (int l = 0; l < 2; ++l) {
        int idx = lane * 2 + l;
        float4 sv = sp[idx], av = ah[idx];
        accs += sv.x*av.x + sv.y*av.y + sv.z*av.z + sv.w*av.w;
        float4 tv = tp[idx], bv = at[idx];
        acct += tv.x*bv.x + tv.y*bv.y + tv.z*bv.z + tv.w*bv.w;
    }
#pragma unroll
    for (int m = 32; m >= 1; m >>= 1) {
        accs += __shfl_xor(accs, m);
        acct += __shfl_xor(acct, m);
    }
    if (lane == 0) { ss[row] = accs; ts[row] = acct; }
}

// ---------------- CSR build ----------------
__global__ __launch_bounds__(256)
void count_kernel(const int* __restrict__ src, int* __restrict__ counts, int E)
{
    int i = blockIdx.x * blockDim.x + threadIdx.x;
    if (i < E) atomicAdd(&counts[src[i]], 1);
}

// exclusive scan of counts[0..n) into offs[0..n], single 1024-thread block
__global__ __launch_bounds__(1024)
void scan_kernel(const int* __restrict__ counts, int* __restrict__ offs, int n)
{
    __shared__ int part[1024];
    const int tid = threadIdx.x;
    const int CH = (n + 1023) / 1024;
    const int base = tid * CH;
    int s = 0;
    for (int i = 0; i < CH; ++i) {
        int idx = base + i;
        if (idx < n) s += counts[idx];
    }
    part[tid] = s;
    __syncthreads();
    for (int d = 1; d < 1024; d <<= 1) {
        int v = 0;
        if (tid >= d) v = part[tid - d];
        __syncthreads();
        if (tid >= d) part[tid] += v;
        __syncthreads();
    }
    int run = (tid == 0) ? 0 : part[tid - 1];
    for (int i = 0; i < CH; ++i) {
        int idx = base + i;
        if (idx < n) { offs[idx] = run; run += counts[idx]; }
    }
    if (tid == 1023) offs[n] = run;
}

__global__ __launch_bounds__(256)
void fill_kernel(const int* __restrict__ src, int* __restrict__ cursor,
                 int* __restrict__ eidx, int E)
{
    int i = blockIdx.x * blockDim.x + threadIdx.x;
    if (i < E) {
        int pos = atomicAdd(&cursor[src[i]], 1);
        eidx[pos] = i;
    }
}

// ---------------- fused GAT aggregate + combine -----------------------------
// One wave per source node s:
//   den = sum_j exp(tanh(ss[s] + ts[tgt_j] + ab))
//   hp  = sum_j w_j * T[tgt_j,:]   (register accumulated, lane-sliced)
//   out[s,:] = (head[s,:] + hp/den + gbias) * 0.5
__global__ __launch_bounds__(256)
void gat_agg_kernel(const int* __restrict__ offs, const int* __restrict__ eidx,
                    const int* __restrict__ tgt, const float* __restrict__ T,
                    const float* __restrict__ ss, const float* __restrict__ ts,
                    const float* __restrict__ ab_ptr, const float* __restrict__ head,
                    const float* __restrict__ gbias, float* __restrict__ out, int N)
{
    int s = blockIdx.x * 4 + (threadIdx.x >> 6);
    int lane = threadIdx.x & 63;
    if (s >= N) return;
    const int beg = offs[s], end = offs[s + 1];
    const float ab = ab_ptr[0];
    const float ss_s = ss[s];
    float4 a0 = make_float4(0.f,0.f,0.f,0.f), a1 = a0;
    float den = 0.f;
    for (int j = beg; j < end; ++j) {
        int e = eidx[j];
        int t = tgt[e];
        float w = expf(tanhf(ss_s + ts[t] + ab));
        den += w;
        const float4* tp = (const float4*)(T + (size_t)t * HH) + lane * 2;
        float4 v0 = tp[0], v1 = tp[1];
        a0.x = fmaf(w, v0.x, a0.x); a0.y = fmaf(w, v0.y, a0.y);
        a0.z = fmaf(w, v0.z, a0.z); a0.w = fmaf(w, v0.w, a0.w);
        a1.x = fmaf(w, v1.x, a1.x); a1.y = fmaf(w, v1.y, a1.y);
        a1.z = fmaf(w, v1.z, a1.z); a1.w = fmaf(w, v1.w, a1.w);
    }
    float inv = (den > 0.f) ? 1.f / den : 0.f;
    const float4* hp = (const float4*)(head + (size_t)s * HH) + lane * 2;
    const float4* bp = (const float4*)gbias + lane * 2;
    float4 h0 = hp[0], h1 = hp[1], b0 = bp[0], b1 = bp[1];
    float4 o0, o1;
    o0.x = (h0.x + a0.x * inv + b0.x) * 0.5f;
    o0.y = (h0.y + a0.y * inv + b0.y) * 0.5f;
    o0.z = (h0.z + a0.z * inv + b0.z) * 0.5f;
    o0.w = (h0.w + a0.w * inv + b0.w) * 0.5f;
    o1.x = (h1.x + a1.x * inv + b1.x) * 0.5f;
    o1.y = (h1.y + a1.y * inv + b1.y) * 0.5f;
    o1.z = (h1.z + a1.z * inv + b1.z) * 0.5f;
    o1.w = (h1.w + a1.w * inv + b1.w) * 0.5f;
    float4* op = (float4*)(out + (size_t)s * HH) + lane * 2;
    op[0] = o0; op[1] = o1;
}

// ---------------- out = LN(tanh(Z [+ res])) * g + b, row-wise (H=512) -------
__global__ __launch_bounds__(256)
void tanh_ln_kernel(const float* __restrict__ Z, const float* __restrict__ res,
                    const float* __restrict__ g, const float* __restrict__ bta,
                    float* __restrict__ out, int N)
{
    int row = blockIdx.x * 4 + (threadIdx.x >> 6);
    int lane = threadIdx.x & 63;
    if (row >= N) return;
    const float4* zp = (const float4*)(Z + (size_t)row * HH);
    float v[8];
    float sum = 0.f, sum2 = 0.f;
#pragma unroll
    for (int l = 0; l < 2; ++l) {
        int idx = lane * 2 + l;
        float4 z = zp[idx];
        if (res) {
            float4 r = ((const float4*)(res + (size_t)row * HH))[idx];
            z.x += r.x; z.y += r.y; z.z += r.z; z.w += r.w;
        }
        float t0 = tanhf(z.x), t1 = tanhf(z.y), t2 = tanhf(z.z), t3 = tanhf(z.w);
        v[l*4+0] = t0; v[l*4+1] = t1; v[l*4+2] = t2; v[l*4+3] = t3;
        sum  += t0 + t1 + t2 + t3;
        sum2 += t0*t0 + t1*t1 + t2*t2 + t3*t3;
    }
#pragma unroll
    for (int m = 32; m >= 1; m >>= 1) {
        sum  += __shfl_xor(sum, m);
        sum2 += __shfl_xor(sum2, m);
    }
    float mu  = sum * (1.f/HH);
    float var = sum2 * (1.f/HH) - mu*mu;
    float rs  = rsqrtf(var + 1e-5f);
#pragma unroll
    for (int l = 0; l < 2; ++l) {
        int idx = lane * 2 + l;
        float4 gv = ((const float4*)g)[idx];
        float4 bv = ((const float4*)bta)[idx];
        float4 o;
        o.x = (v[l*4+0]-mu)*rs*gv.x + bv.x;
        o.y = (v[l*4+1]-mu)*rs*gv.y + bv.y;
        o.z = (v[l*4+2]-mu)*rs*gv.z + bv.z;
        o.w = (v[l*4+3]-mu)*rs*gv.w + bv.w;
        ((float4*)(out + (size_t)row * HH))[idx] = o;
    }
}

// ---------------- out[n] = sigmoid(X[n,:].Wc + bc) ---------------------------
__global__ __launch_bounds__(256)
void cls_kernel(const float* __restrict__ X, const float* __restrict__ Wc,
                const float* __restrict__ bc, float* __restrict__ out, int N)
{
    int row = blockIdx.x * 4 + (threadIdx.x >> 6);
    int lane = threadIdx.x & 63;
    if (row >= N) return;
    const float4* xp = (const float4*)(X + (size_t)row * HH);
    const float4* wp = (const float4*)Wc;
    float acc = 0.f;
#pragma unroll
    for (int l = 0; l < 2; ++l) {
        int idx = lane * 2 + l;
        float4 x = xp[idx], w = wp[idx];
        acc += x.x*w.x + x.y*w.y + x.z*w.z + x.w*w.w;
    }
#pragma unroll
    for (int m = 32; m >= 1; m >>= 1) acc += __shfl_xor(acc, m);
    if (lane == 0) out[row] = 1.f / (1.f + expf(-(acc + bc[0])));
}

extern "C" void kernel_launch(void* const* d_in, const int* in_sizes, int n_in,
                              void* d_out, int out_size, void* d_ws, size_t ws_size,
                              hipStream_t stream)
{
    (void)in_sizes; (void)n_in; (void)out_size; (void)ws_size;
    const int N = NN, E = NE, H = HH;
    const size_t NHf = (size_t)N * H;

    const float* fu0 = (const float*)d_in[0];
    const float* fi1 = (const float*)d_in[3];
    const float* fu2 = (const float*)d_in[4];
    const int* eUI0 = (const int*)d_in[6];
    const int* eIU1 = (const int*)d_in[9];
    const float* Wu  = (const float*)d_in[10];
    const float* bu  = (const float*)d_in[11];
    const float* Wi  = (const float*)d_in[12];
    const float* bi  = (const float*)d_in[13];
    const float* gfW = (const float*)d_in[14];
    const float* gfb = (const float*)d_in[15];
    const float* gaw = (const float*)d_in[16];
    const float* gab = (const float*)d_in[17];
    const float* gbias = (const float*)d_in[18];
    const float* prW = (const float*)d_in[19];
    const float* prb = (const float*)d_in[20];
    const float* dW  = (const float*)d_in[21];
    const float* db  = (const float*)d_in[22];
    const float* dlg = (const float*)d_in[23];
    const float* dlb = (const float*)d_in[24];
    const float* rlg = (const float*)d_in[25];
    const float* rlb = (const float*)d_in[26];
    const float* cW  = (const float*)d_in[27];
    const float* cb  = (const float*)d_in[28];

    float* B0 = (float*)d_ws;        // su (h2) -> later su_final
    float* B1 = B0 + NHf;            // hi (h1) -> si_new (in place)
    float* B2 = B1 + NHf;            // hu0 / x
    float* B3 = B2 + NHf;            // s scratch / dnn gemm out
    float* B4 = B3 + NHf;            // t scratch
    float* B5 = B4 + NHf;            // residual save
    float* ssb  = B5 + NHf;          // [N]
    float* tsb  = ssb + N;           // [N]
    int* counts = (int*)(tsb + N);   // [N]
    int* offs   = counts + N;        // [N+1]
    int* cursor = offs + N + 1;      // [N]
    int* eidx   = cursor + N;        // [E]

    dim3 gblk(256);
    dim3 ggrd(8, (N + 127) / 128);
    auto LIN = [&](const float* X, const float* W, const float* b, float* o, int K) {
        hipLaunchKernelGGL(lin_kernel, ggrd, gblk, 0, stream, X, W, b, o, N, K);
    };
    const int rgrid = (N + 3) / 4;
    const int egrid = (E + 255) / 256;

    // GAT(r, head, tail, edges) -> out = (head + (agg + gat_bias)) * 0.5
    auto GAT = [&](int r, const float* head, const float* tail, const int* edges, float* out) {
        LIN(head, gfW + (size_t)r*H*H, gfb + r*H, B3, H);
        LIN(tail, gfW + (size_t)r*H*H, gfb + r*H, B4, H);
        hipLaunchKernelGGL(rowdot_kernel, dim3(rgrid), dim3(256), 0, stream,
                           B3, B4, gaw + r*2*H, ssb, tsb, N);
        hipMemsetAsync(counts, 0, N*sizeof(int), stream);
        hipLaunchKernelGGL(count_kernel, dim3(egrid), dim3(256), 0, stream,
                           edges, counts, E);
        hipLaunchKernelGGL(scan_kernel, dim3(1), dim3(1024), 0, stream,
                           counts, offs, N);
        hipMemcpyAsync(cursor, offs, N*sizeof(int), hipMemcpyDeviceToDevice, stream);
        hipLaunchKernelGGL(fill_kernel, dim3(egrid), dim3(256), 0, stream,
                           edges, cursor, eidx, E);
        hipLaunchKernelGGL(gat_agg_kernel, dim3(rgrid), dim3(256), 0, stream,
                           offs, eidx, edges + E, B4, ssb, tsb, gab + r,
                           head, gbias + (size_t)r*H, out, N);
    };

    // hop-2 / hop-1 live transforms
    LIN(fu2, Wu, bu, B0, 512);       // su  = user_h2 transform
    LIN(fi1, Wi, bi, B1, 256);       // hi  = item_h1 transform
    GAT(1, B1, B0, eIU1, B1);        // si_new = (hi + GAT1(hi, su)) * 0.5 (in place)
    LIN(fu0, Wu, bu, B2, 512);       // hu0
    GAT(0, B2, B1, eUI0, B0);        // su_final

    // Res_DNN head
    LIN(B0, prW, prb, B2, 512);      // x in B2
    for (int r = 0; r < 2; ++r) {
        hipMemcpyAsync(B5, B2, NHf*sizeof(float), hipMemcpyDeviceToDevice, stream); // sc
        for (int d = 0; d < 2; ++d) {
            LIN(B2, dW + ((size_t)(r*2+d))*H*H, db + (r*2+d)*H, B3, 512);
            hipLaunchKernelGGL(tanh_ln_kernel, dim3(rgrid), dim3(256), 0, stream,
                               B3, (const float*)nullptr, dlg + (r*2+d)*H, dlb + (r*2+d)*H, B2, N);
        }
        hipLaunchKernelGGL(tanh_ln_kernel, dim3(rgrid), dim3(256), 0, stream,
                           B2, B5, rlg + r*H, rlb + r*H, B2, N);
    }
    hipLaunchKernelGGL(cls_kernel, dim3(rgrid), dim3(256), 0, stream,
                       B2, cW, cb, (float*)d_out, N);
}

// Round 3
// 790.988 us; speedup vs baseline: 9.3306x; 2.6742x over previous
//
#include <hip/hip_runtime.h>
#include <math.h>

#define NN 20000
#define NE 200000
#define HH 512

typedef __attribute__((ext_vector_type(8))) short short8v;
typedef __attribute__((ext_vector_type(4))) float f32x4;

__device__ inline short f2bf(float f) {
    union { float f; unsigned u; } v; v.f = f;
    unsigned r = (v.u + 0x7fffu + ((v.u >> 16) & 1u)) >> 16;
    return (short)r;
}

// ---------------- weight transpose + bf16 convert: dst[n][k] = src[k][n] ----
__global__ __launch_bounds__(256)
void wtr_kernel(const float* __restrict__ src, short* __restrict__ dst,
                int K, int Ncols)
{
    __shared__ float t[32][33];
    int bx = blockIdx.x * 32;   // col (n)
    int by = blockIdx.y * 32;   // row (k)
    int tx = threadIdx.x, ty = threadIdx.y;
    for (int i = ty; i < 32; i += 8)
        t[i][tx] = src[(size_t)(by + i) * Ncols + bx + tx];
    __syncthreads();
    for (int i = ty; i < 32; i += 8)
        dst[(size_t)(bx + i) * K + by + tx] = f2bf(t[tx][i]);
}

// ---------------- MFMA GEMM: out[M,512] = X[M,K](fp32) @ WT[512,K](bf16)^T + b
// 128x128 tile, BK=32, 4 waves (2x2), each wave 64x64 (4x4 frags of 16x16x32).
__global__ __launch_bounds__(256)
void mfma_lin(const float* __restrict__ X, const short* __restrict__ WT,
              const float* __restrict__ bias, float* __restrict__ out,
              int M, int K)
{
    __shared__ short8v As[2][512];   // [row 0..127][chunk 0..3], chunk-XOR swizzled
    __shared__ short8v Bs[2][512];

    const int tid = threadIdx.x;
    const int lane = tid & 63;
    const int w = tid >> 6;

    // XCD-chunked bijective swizzle over 1D grid (col fastest within a band)
    const int nby = (M + 127) >> 7;
    const int nwg = nby << 2;
    const int q = nwg >> 3, r = nwg & 7;
    int id = blockIdx.x;
    int xcd = id & 7, wi = id >> 3;
    int wgid = (xcd < r ? xcd * (q + 1) : r * (q + 1) + (xcd - r) * q) + wi;
    const int col0 = (wgid & 3) * 128;
    const int row0 = (wgid >> 2) * 128;

    const int wr = (w >> 1) * 64;
    const int wc = (w & 1) * 64;

    // staging: thread -> row=tid>>1 (0..127), k-chunk pair sc0=(tid&1)*2
    const int srow = tid >> 1;
    const int sc0 = (tid & 1) * 2;
    const int arow_g = row0 + srow;
    const float* aptr = X + (size_t)arow_g * K + sc0 * 8;
    const short* bptr = WT + (size_t)(col0 + srow) * K + sc0 * 8;
    const int swz = (srow >> 1) & 3;
    const int wi0 = srow * 4 + (sc0 ^ swz);
    const int wi1 = srow * 4 + ((sc0 + 1) ^ swz);
    const bool avalid = (arow_g < M);

    // fragment read indices
    int ar[4], br[4];
#pragma unroll
    for (int i = 0; i < 4; ++i) {
        int rr = wr + i * 16 + (lane & 15);
        ar[i] = rr * 4 + ((lane >> 4) ^ ((rr >> 1) & 3));
        int nn = wc + i * 16 + (lane & 15);
        br[i] = nn * 4 + ((lane >> 4) ^ ((nn >> 1) & 3));
    }

    f32x4 acc[4][4];
#pragma unroll
    for (int i = 0; i < 4; ++i)
#pragma unroll
        for (int j = 0; j < 4; ++j)
            acc[i][j] = (f32x4){0.f, 0.f, 0.f, 0.f};

    float4 v0, v1, v2, v3;
    short8v c0, c1;
    auto loadT = [&](int kk) {
        if (avalid) {
            const float4* p = (const float4*)(aptr + kk);
            v0 = p[0]; v1 = p[1]; v2 = p[2]; v3 = p[3];
        } else {
            v0 = v1 = v2 = v3 = make_float4(0.f, 0.f, 0.f, 0.f);
        }
        const short8v* bp = (const short8v*)(bptr + kk);
        c0 = bp[0]; c1 = bp[1];
    };
    auto writeT = [&](int buf) {
        short8v s0, s1;
        s0[0] = f2bf(v0.x); s0[1] = f2bf(v0.y); s0[2] = f2bf(v0.z); s0[3] = f2bf(v0.w);
        s0[4] = f2bf(v1.x); s0[5] = f2bf(v1.y); s0[6] = f2bf(v1.z); s0[7] = f2bf(v1.w);
        s1[0] = f2bf(v2.x); s1[1] = f2bf(v2.y); s1[2] = f2bf(v2.z); s1[3] = f2bf(v2.w);
        s1[4] = f2bf(v3.x); s1[5] = f2bf(v3.y); s1[6] = f2bf(v3.z); s1[7] = f2bf(v3.w);
        As[buf][wi0] = s0; As[buf][wi1] = s1;
        Bs[buf][wi0] = c0; Bs[buf][wi1] = c1;
    };

    const int nt = K >> 5;
    loadT(0);
    writeT(0);
    __syncthreads();
    int cur = 0;
    for (int t = 0; t < nt; ++t) {
        if (t + 1 < nt) loadT((t + 1) * 32);
        short8v af[4], bf[4];
#pragma unroll
        for (int i = 0; i < 4; ++i) af[i] = As[cur][ar[i]];
#pragma unroll
        for (int j = 0; j < 4; ++j) bf[j] = Bs[cur][br[j]];
#pragma unroll
        for (int i = 0; i < 4; ++i)
#pragma unroll
            for (int j = 0; j < 4; ++j)
                acc[i][j] = __builtin_amdgcn_mfma_f32_16x16x32_bf16(af[i], bf[j], acc[i][j], 0, 0, 0);
        if (t + 1 < nt) writeT(cur ^ 1);
        __syncthreads();
        cur ^= 1;
    }

    float bj[4];
#pragma unroll
    for (int j = 0; j < 4; ++j)
        bj[j] = bias[col0 + wc + j * 16 + (lane & 15)];
#pragma unroll
    for (int i = 0; i < 4; ++i) {
#pragma unroll
        for (int rr = 0; rr < 4; ++rr) {
            int row = row0 + wr + i * 16 + (lane >> 4) * 4 + rr;
            if (row < M) {
                float* op = out + (size_t)row * HH + col0 + wc + (lane & 15);
#pragma unroll
                for (int j = 0; j < 4; ++j)
                    op[j * 16] = acc[i][j][rr] + bj[j];
            }
        }
    }
}

// ---------------- gat_pre: u = fW @ aw[:512], v = fW @ aw[512:], fb dots -----
__global__ __launch_bounds__(256)
void gat_pre_kernel(const float* __restrict__ fW, const float* __restrict__ fb,
                    const float* __restrict__ aw, float* __restrict__ uv,
                    float* __restrict__ s0t0)
{
    int row = blockIdx.x * 4 + (threadIdx.x >> 6);
    int lane = threadIdx.x & 63;
    const float4* ah = (const float4*)aw;
    const float4* at = (const float4*)(aw + HH);
    if (row < 512) {
        const float4* fp = (const float4*)(fW + (size_t)row * HH);
        float du = 0.f, dv = 0.f;
#pragma unroll
        for (int l = 0; l < 2; ++l) {
            int idx = lane * 2 + l;
            float4 f = fp[idx], a = ah[idx], b = at[idx];
            du += f.x*a.x + f.y*a.y + f.z*a.z + f.w*a.w;
            dv += f.x*b.x + f.y*b.y + f.z*b.z + f.w*b.w;
        }
#pragma unroll
        for (int m = 32; m >= 1; m >>= 1) {
            du += __shfl_xor(du, m);
            dv += __shfl_xor(dv, m);
        }
        if (lane == 0) { uv[row] = du; uv[512 + row] = dv; }
    } else if (row == 512) {
        const float4* fp = (const float4*)fb;
        float du = 0.f, dv = 0.f;
#pragma unroll
        for (int l = 0; l < 2; ++l) {
            int idx = lane * 2 + l;
            float4 f = fp[idx], a = ah[idx], b = at[idx];
            du += f.x*a.x + f.y*a.y + f.z*a.z + f.w*a.w;
            dv += f.x*b.x + f.y*b.y + f.z*b.z + f.w*b.w;
        }
#pragma unroll
        for (int m = 32; m >= 1; m >>= 1) {
            du += __shfl_xor(du, m);
            dv += __shfl_xor(dv, m);
        }
        if (lane == 0) { s0t0[0] = du; s0t0[1] = dv; }
    }
}

// ---------------- rowdot2: ss[n]=Head[n].u+s0, ts[n]=Tail[n].v+t0 ------------
__global__ __launch_bounds__(256)
void rowdot2_kernel(const float* __restrict__ Hd, const float* __restrict__ Tl,
                    const float* __restrict__ uv, const float* __restrict__ s0t0,
                    float* __restrict__ ss, float* __restrict__ ts, int N)
{
    int row = blockIdx.x * 4 + (threadIdx.x >> 6);
    int lane = threadIdx.x & 63;
    if (row >= N) return;
    const float4* hp = (const float4*)(Hd + (size_t)row * HH);
    const float4* tp = (const float4*)(Tl + (size_t)row * HH);
    const float4* up = (const float4*)uv;
    const float4* vp = (const float4*)(uv + HH);
    float a = 0.f, b = 0.f;
#pragma unroll
    for (int l = 0; l < 2; ++l) {
        int idx = lane * 2 + l;
        float4 h = hp[idx], u = up[idx];
        a += h.x*u.x + h.y*u.y + h.z*u.z + h.w*u.w;
        float4 t = tp[idx], v = vp[idx];
        b += t.x*v.x + t.y*v.y + t.z*v.z + t.w*v.w;
    }
#pragma unroll
    for (int m = 32; m >= 1; m >>= 1) {
        a += __shfl_xor(a, m);
        b += __shfl_xor(b, m);
    }
    if (lane == 0) { ss[row] = a + s0t0[0]; ts[row] = b + s0t0[1]; }
}

// ---------------- CSR build ----------------
__global__ __launch_bounds__(256)
void count_kernel(const int* __restrict__ src, int* __restrict__ counts, int E)
{
    int i = blockIdx.x * blockDim.x + threadIdx.x;
    if (i < E) atomicAdd(&counts[src[i]], 1);
}

__global__ __launch_bounds__(1024)
void scan_kernel(const int* __restrict__ counts, int* __restrict__ offs, int n)
{
    __shared__ int part[1024];
    const int tid = threadIdx.x;
    const int CH = (n + 1023) / 1024;
    const int base = tid * CH;
    int s = 0;
    for (int i = 0; i < CH; ++i) {
        int idx = base + i;
        if (idx < n) s += counts[idx];
    }
    part[tid] = s;
    __syncthreads();
    for (int d = 1; d < 1024; d <<= 1) {
        int v = 0;
        if (tid >= d) v = part[tid - d];
        __syncthreads();
        if (tid >= d) part[tid] += v;
        __syncthreads();
    }
    int run = (tid == 0) ? 0 : part[tid - 1];
    for (int i = 0; i < CH; ++i) {
        int idx = base + i;
        if (idx < n) { offs[idx] = run; run += counts[idx]; }
    }
    if (tid == 1023) offs[n] = run;
}

__global__ __launch_bounds__(256)
void fill_kernel(const int* __restrict__ src, int* __restrict__ cursor,
                 int* __restrict__ eidx, int E)
{
    int i = blockIdx.x * blockDim.x + threadIdx.x;
    if (i < E) {
        int pos = atomicAdd(&cursor[src[i]], 1);
        eidx[pos] = i;
    }
}

// ---------------- fused GAT aggregate + combine -----------------------------
__global__ __launch_bounds__(256)
void gat_agg_kernel(const int* __restrict__ offs, const int* __restrict__ eidx,
                    const int* __restrict__ tgt, const float* __restrict__ T,
                    const float* __restrict__ ss, const float* __restrict__ ts,
                    const float* __restrict__ ab_ptr, const float* __restrict__ head,
                    const float* __restrict__ gbias, float* __restrict__ out, int N)
{
    int s = blockIdx.x * 4 + (threadIdx.x >> 6);
    int lane = threadIdx.x & 63;
    if (s >= N) return;
    const int beg = offs[s], end = offs[s + 1];
    const float ab = ab_ptr[0];
    const float ss_s = ss[s];
    float4 a0 = make_float4(0.f,0.f,0.f,0.f), a1 = a0;
    float den = 0.f;
    for (int j = beg; j < end; ++j) {
        int e = eidx[j];
        int t = tgt[e];
        float w = expf(tanhf(ss_s + ts[t] + ab));
        den += w;
        const float4* tp = (const float4*)(T + (size_t)t * HH) + lane * 2;
        float4 q0 = tp[0], q1 = tp[1];
        a0.x = fmaf(w, q0.x, a0.x); a0.y = fmaf(w, q0.y, a0.y);
        a0.z = fmaf(w, q0.z, a0.z); a0.w = fmaf(w, q0.w, a0.w);
        a1.x = fmaf(w, q1.x, a1.x); a1.y = fmaf(w, q1.y, a1.y);
        a1.z = fmaf(w, q1.z, a1.z); a1.w = fmaf(w, q1.w, a1.w);
    }
    float inv = (den > 0.f) ? 1.f / den : 0.f;
    const float4* hp = (const float4*)(head + (size_t)s * HH) + lane * 2;
    const float4* bp = (const float4*)gbias + lane * 2;
    float4 h0 = hp[0], h1 = hp[1], b0 = bp[0], b1 = bp[1];
    float4 o0, o1;
    o0.x = (h0.x + a0.x * inv + b0.x) * 0.5f;
    o0.y = (h0.y + a0.y * inv + b0.y) * 0.5f;
    o0.z = (h0.z + a0.z * inv + b0.z) * 0.5f;
    o0.w = (h0.w + a0.w * inv + b0.w) * 0.5f;
    o1.x = (h1.x + a1.x * inv + b1.x) * 0.5f;
    o1.y = (h1.y + a1.y * inv + b1.y) * 0.5f;
    o1.z = (h1.z + a1.z * inv + b1.z) * 0.5f;
    o1.w = (h1.w + a1.w * inv + b1.w) * 0.5f;
    float4* op = (float4*)(out + (size_t)s * HH) + lane * 2;
    op[0] = o0; op[1] = o1;
}

// ---------------- out = LN(tanh(Z [+ res])) * g + b, row-wise (H=512) -------
__global__ __launch_bounds__(256)
void tanh_ln_kernel(const float* __restrict__ Z, const float* __restrict__ res,
                    const float* __restrict__ g, const float* __restrict__ bta,
                    float* __restrict__ out, int N)
{
    int row = blockIdx.x * 4 + (threadIdx.x >> 6);
    int lane = threadIdx.x & 63;
    if (row >= N) return;
    const float4* zp = (const float4*)(Z + (size_t)row * HH);
    float v[8];
    float sum = 0.f, sum2 = 0.f;
#pragma unroll
    for (int l = 0; l < 2; ++l) {
        int idx = lane * 2 + l;
        float4 z = zp[idx];
        if (res) {
            float4 r = ((const float4*)(res + (size_t)row * HH))[idx];
            z.x += r.x; z.y += r.y; z.z += r.z; z.w += r.w;
        }
        float t0 = tanhf(z.x), t1 = tanhf(z.y), t2 = tanhf(z.z), t3 = tanhf(z.w);
        v[l*4+0] = t0; v[l*4+1] = t1; v[l*4+2] = t2; v[l*4+3] = t3;
        sum  += t0 + t1 + t2 + t3;
        sum2 += t0*t0 + t1*t1 + t2*t2 + t3*t3;
    }
#pragma unroll
    for (int m = 32; m >= 1; m >>= 1) {
        sum  += __shfl_xor(sum, m);
        sum2 += __shfl_xor(sum2, m);
    }
    float mu  = sum * (1.f/HH);
    float var = sum2 * (1.f/HH) - mu*mu;
    float rs  = rsqrtf(var + 1e-5f);
#pragma unroll
    for (int l = 0; l < 2; ++l) {
        int idx = lane * 2 + l;
        float4 gv = ((const float4*)g)[idx];
        float4 bv = ((const float4*)bta)[idx];
        float4 o;
        o.x = (v[l*4+0]-mu)*rs*gv.x + bv.x;
        o.y = (v[l*4+1]-mu)*rs*gv.y + bv.y;
        o.z = (v[l*4+2]-mu)*rs*gv.z + bv.z;
        o.w = (v[l*4+3]-mu)*rs*gv.w + bv.w;
        ((float4*)(out + (size_t)row * HH))[idx] = o;
    }
}

// ---------------- out[n] = sigmoid(X[n,:].Wc + bc) ---------------------------
__global__ __launch_bounds__(256)
void cls_kernel(const float* __restrict__ X, const float* __restrict__ Wc,
                const float* __restrict__ bc, float* __restrict__ out, int N)
{
    int row = blockIdx.x * 4 + (threadIdx.x >> 6);
    int lane = threadIdx.x & 63;
    if (row >= N) return;
    const float4* xp = (const float4*)(X + (size_t)row * HH);
    const float4* wp = (const float4*)Wc;
    float acc = 0.f;
#pragma unroll
    for (int l = 0; l < 2; ++l) {
        int idx = lane * 2 + l;
        float4 x = xp[idx], w = wp[idx];
        acc += x.x*w.x + x.y*w.y + x.z*w.z + x.w*w.w;
    }
#pragma unroll
    for (int m = 32; m >= 1; m >>= 1) acc += __shfl_xor(acc, m);
    if (lane == 0) out[row] = 1.f / (1.f + expf(-(acc + bc[0])));
}

extern "C" void kernel_launch(void* const* d_in, const int* in_sizes, int n_in,
                              void* d_out, int out_size, void* d_ws, size_t ws_size,
                              hipStream_t stream)
{
    (void)in_sizes; (void)n_in; (void)out_size; (void)ws_size;
    const int N = NN, E = NE, H = HH;
    const size_t NHf = (size_t)N * H;

    const float* fu0 = (const float*)d_in[0];
    const float* fi1 = (const float*)d_in[3];
    const float* fu2 = (const float*)d_in[4];
    const int* eUI0 = (const int*)d_in[6];
    const int* eIU1 = (const int*)d_in[9];
    const float* Wu  = (const float*)d_in[10];
    const float* bu  = (const float*)d_in[11];
    const float* Wi  = (const float*)d_in[12];
    const float* bi  = (const float*)d_in[13];
    const float* gfW = (const float*)d_in[14];
    const float* gfb = (const float*)d_in[15];
    const float* gaw = (const float*)d_in[16];
    const float* gab = (const float*)d_in[17];
    const float* gbias = (const float*)d_in[18];
    const float* prW = (const float*)d_in[19];
    const float* prb = (const float*)d_in[20];
    const float* dW  = (const float*)d_in[21];
    const float* db  = (const float*)d_in[22];
    const float* dlg = (const float*)d_in[23];
    const float* dlb = (const float*)d_in[24];
    const float* rlg = (const float*)d_in[25];
    const float* rlb = (const float*)d_in[26];
    const float* cW  = (const float*)d_in[27];
    const float* cb  = (const float*)d_in[28];

    float* B0 = (float*)d_ws;
    float* B1 = B0 + NHf;
    float* B2 = B1 + NHf;
    float* B3 = B2 + NHf;
    float* B4 = B3 + NHf;
    float* B5 = B4 + NHf;
    float* ssb  = B5 + NHf;          // [N]
    float* tsb  = ssb + N;           // [N]
    float* uv   = tsb + N;           // [1024]
    float* s0t0 = uv + 1024;         // [2] (+pad)
    int* counts = (int*)(s0t0 + 4);  // [N]
    int* offs   = counts + N;        // [N+1]
    int* cursor = offs + N + 1;      // [N]
    int* eidx   = cursor + N;        // [E]
    size_t boff = (size_t)((char*)(eidx + E) - (char*)d_ws);
    boff = (boff + 15) & ~(size_t)15;
    short* WTu  = (short*)((char*)d_ws + boff);
    short* WTi  = WTu + 512 * 512;
    short* WTg0 = WTi + 512 * 256;
    short* WTg1 = WTg0 + 512 * 512;
    short* WTpr = WTg1 + 512 * 512;
    short* WTd  = WTpr + 512 * 512;   // 4 x 512*512

    // ---- weight pre-pass: transpose + bf16 ----
    auto WTR = [&](const float* src, short* dst, int K) {
        hipLaunchKernelGGL(wtr_kernel, dim3(16, K / 32), dim3(32, 8), 0, stream,
                           src, dst, K, 512);
    };
    WTR(Wu, WTu, 512);
    WTR(Wi, WTi, 256);
    WTR(gfW, WTg0, 512);
    WTR(gfW + (size_t)H * H, WTg1, 512);
    WTR(prW, WTpr, 512);
    for (int k = 0; k < 4; ++k)
        WTR(dW + (size_t)k * H * H, WTd + (size_t)k * 512 * 512, 512);

    const int nby = (N + 127) / 128;
    const int nwg = nby * 4;
    auto MLIN = [&](const float* X, const short* WT, const float* b, float* o, int K) {
        hipLaunchKernelGGL(mfma_lin, dim3(nwg), dim3(256), 0, stream, X, WT, b, o, N, K);
    };
    const int rgrid = (N + 3) / 4;
    const int egrid = (E + 255) / 256;

    auto GAT = [&](int r, const float* head, const float* tail, const short* WTg,
                   const int* edges, float* out) {
        hipLaunchKernelGGL(gat_pre_kernel, dim3(129), dim3(256), 0, stream,
                           gfW + (size_t)r * H * H, gfb + r * H, gaw + (size_t)r * 2 * H,
                           uv, s0t0);
        MLIN(tail, WTg, gfb + r * H, B4, 512);
        hipLaunchKernelGGL(rowdot2_kernel, dim3(rgrid), dim3(256), 0, stream,
                           head, tail, uv, s0t0, ssb, tsb, N);
        hipMemsetAsync(counts, 0, N * sizeof(int), stream);
        hipLaunchKernelGGL(count_kernel, dim3(egrid), dim3(256), 0, stream,
                           edges, counts, E);
        hipLaunchKernelGGL(scan_kernel, dim3(1), dim3(1024), 0, stream,
                           counts, offs, N);
        hipMemcpyAsync(cursor, offs, N * sizeof(int), hipMemcpyDeviceToDevice, stream);
        hipLaunchKernelGGL(fill_kernel, dim3(egrid), dim3(256), 0, stream,
                           edges, cursor, eidx, E);
        hipLaunchKernelGGL(gat_agg_kernel, dim3(rgrid), dim3(256), 0, stream,
                           offs, eidx, edges + E, B4, ssb, tsb, gab + r,
                           head, gbias + (size_t)r * H, out, N);
    };

    // hop-2 / hop-1 live transforms
    MLIN(fu2, WTu, bu, B0, 512);       // su
    MLIN(fi1, WTi, bi, B1, 256);       // hi
    GAT(1, B1, B0, WTg1, eIU1, B1);    // si_new (in place)
    MLIN(fu0, WTu, bu, B2, 512);       // hu0
    GAT(0, B2, B1, WTg0, eUI0, B0);    // su_final

    // Res_DNN head
    MLIN(B0, WTpr, prb, B2, 512);      // x in B2
    for (int r = 0; r < 2; ++r) {
        hipMemcpyAsync(B5, B2, NHf * sizeof(float), hipMemcpyDeviceToDevice, stream);
        for (int d = 0; d < 2; ++d) {
            MLIN(B2, WTd + (size_t)(r * 2 + d) * 512 * 512, db + (r * 2 + d) * H, B3, 512);
            hipLaunchKernelGGL(tanh_ln_kernel, dim3(rgrid), dim3(256), 0, stream,
                               B3, (const float*)nullptr, dlg + (r * 2 + d) * H,
                               dlb + (r * 2 + d) * H, B2, N);
        }
        hipLaunchKernelGGL(tanh_ln_kernel, dim3(rgrid), dim3(256), 0, stream,
                           B2, B5, rlg + r * H, rlb + r * H, B2, N);
    }
    hipLaunchKernelGGL(cls_kernel, dim3(rgrid), dim3(256), 0, stream,
                       B2, cW, cb, (float*)d_out, N);
}

// Round 4
// 640.376 us; speedup vs baseline: 11.5252x; 1.2352x over previous
//
#include <hip/hip_runtime.h>
#include <math.h>

#define NN 20000
#define NE 200000
#define HH 512

typedef __attribute__((ext_vector_type(8))) short short8v;
typedef __attribute__((ext_vector_type(4))) float f32x4;

__device__ inline short f2bf(float f) {
    union { float f; unsigned u; } v; v.f = f;
    unsigned r = (v.u + 0x7fffu + ((v.u >> 16) & 1u)) >> 16;
    return (short)r;
}
__device__ inline float bf2f(short s) {
    union { unsigned u; float f; } v;
    v.u = ((unsigned)(unsigned short)s) << 16;
    return v.f;
}

// ---------------- fp32 -> bf16 bulk convert (8 elems/thread) ----------------
__global__ __launch_bounds__(256)
void f2b_kernel(const float* __restrict__ src, short* __restrict__ dst, int n8)
{
    int i = blockIdx.x * 256 + threadIdx.x;
    if (i >= n8) return;
    const float4* p = (const float4*)src + (size_t)i * 2;
    float4 a = p[0], b = p[1];
    short8v s;
    s[0] = f2bf(a.x); s[1] = f2bf(a.y); s[2] = f2bf(a.z); s[3] = f2bf(a.w);
    s[4] = f2bf(b.x); s[5] = f2bf(b.y); s[6] = f2bf(b.z); s[7] = f2bf(b.w);
    ((short8v*)dst)[i] = s;
}

// ---------------- weight transpose + bf16 convert: dst[n][k] = src[k][n] ----
__global__ __launch_bounds__(256)
void wtr_kernel(const float* __restrict__ src, short* __restrict__ dst,
                int K, int Ncols)
{
    __shared__ float t[32][33];
    int bx = blockIdx.x * 32;
    int by = blockIdx.y * 32;
    int tx = threadIdx.x, ty = threadIdx.y;
    for (int i = ty; i < 32; i += 8)
        t[i][tx] = src[(size_t)(by + i) * Ncols + bx + tx];
    __syncthreads();
    for (int i = ty; i < 32; i += 8)
        dst[(size_t)(bx + i) * K + by + tx] = f2bf(t[tx][i]);
}

// ---------------- MFMA GEMM: out[M,512] = X[M,K](bf16) @ WT[512,K](bf16)^T + b
// 128x128 tile, BK=32, 4 waves (2x2), each wave 64x64 (4x4 frags of 16x16x32).
// outF (fp32) and/or outB (bf16) destinations, either may be null.
__global__ __launch_bounds__(256)
void mfma_lin(const short* __restrict__ X, const short* __restrict__ WT,
              const float* __restrict__ bias, float* __restrict__ outF,
              short* __restrict__ outB, int M, int K)
{
    __shared__ short8v As[2][512];   // [row 0..127][chunk 0..3], chunk-XOR swizzled
    __shared__ short8v Bs[2][512];

    const int tid = threadIdx.x;
    const int lane = tid & 63;
    const int w = tid >> 6;

    // XCD-chunked bijective swizzle over 1D grid
    const int nby = (M + 127) >> 7;
    const int nwg = nby << 2;
    const int q = nwg >> 3, r = nwg & 7;
    int id = blockIdx.x;
    int xcd = id & 7, wi = id >> 3;
    int wgid = (xcd < r ? xcd * (q + 1) : r * (q + 1) + (xcd - r) * q) + wi;
    const int col0 = (wgid & 3) * 128;
    const int row0 = (wgid >> 2) * 128;

    const int wr = (w >> 1) * 64;
    const int wc = (w & 1) * 64;

    const int srow = tid >> 1;
    const int sc0 = (tid & 1) * 2;
    const int arow_g = row0 + srow;
    const short* aptr = X + (size_t)arow_g * K + sc0 * 8;
    const short* bptr = WT + (size_t)(col0 + srow) * K + sc0 * 8;
    const int swz = (srow >> 1) & 3;
    const int wi0 = srow * 4 + (sc0 ^ swz);
    const int wi1 = srow * 4 + ((sc0 + 1) ^ swz);
    const bool avalid = (arow_g < M);

    int ar[4], br[4];
#pragma unroll
    for (int i = 0; i < 4; ++i) {
        int rr = wr + i * 16 + (lane & 15);
        ar[i] = rr * 4 + ((lane >> 4) ^ ((rr >> 1) & 3));
        int nn = wc + i * 16 + (lane & 15);
        br[i] = nn * 4 + ((lane >> 4) ^ ((nn >> 1) & 3));
    }

    f32x4 acc[4][4];
#pragma unroll
    for (int i = 0; i < 4; ++i)
#pragma unroll
        for (int j = 0; j < 4; ++j)
            acc[i][j] = (f32x4){0.f, 0.f, 0.f, 0.f};

    short8v a0, a1, b0, b1;
    auto loadT = [&](int kk) {
        if (avalid) {
            const short8v* ap = (const short8v*)(aptr + kk);
            a0 = ap[0]; a1 = ap[1];
        } else {
#pragma unroll
            for (int z = 0; z < 8; ++z) { a0[z] = 0; a1[z] = 0; }
        }
        const short8v* bp = (const short8v*)(bptr + kk);
        b0 = bp[0]; b1 = bp[1];
    };
    auto writeT = [&](int buf) {
        As[buf][wi0] = a0; As[buf][wi1] = a1;
        Bs[buf][wi0] = b0; Bs[buf][wi1] = b1;
    };

    const int nt = K >> 5;
    loadT(0);
    writeT(0);
    __syncthreads();
    int cur = 0;
    for (int t = 0; t < nt; ++t) {
        if (t + 1 < nt) loadT((t + 1) * 32);
        short8v af[4], bf[4];
#pragma unroll
        for (int i = 0; i < 4; ++i) af[i] = As[cur][ar[i]];
#pragma unroll
        for (int j = 0; j < 4; ++j) bf[j] = Bs[cur][br[j]];
#pragma unroll
        for (int i = 0; i < 4; ++i)
#pragma unroll
            for (int j = 0; j < 4; ++j)
                acc[i][j] = __builtin_amdgcn_mfma_f32_16x16x32_bf16(af[i], bf[j], acc[i][j], 0, 0, 0);
        if (t + 1 < nt) writeT(cur ^ 1);
        __syncthreads();
        cur ^= 1;
    }

    float bj[4];
#pragma unroll
    for (int j = 0; j < 4; ++j)
        bj[j] = bias[col0 + wc + j * 16 + (lane & 15)];
#pragma unroll
    for (int i = 0; i < 4; ++i) {
#pragma unroll
        for (int rr = 0; rr < 4; ++rr) {
            int row = row0 + wr + i * 16 + (lane >> 4) * 4 + rr;
            if (row < M) {
                size_t base = (size_t)row * HH + col0 + wc + (lane & 15);
                if (outF) {
                    float* op = outF + base;
#pragma unroll
                    for (int j = 0; j < 4; ++j) op[j * 16] = acc[i][j][rr] + bj[j];
                }
                if (outB) {
                    short* op = outB + base;
#pragma unroll
                    for (int j = 0; j < 4; ++j) op[j * 16] = f2bf(acc[i][j][rr] + bj[j]);
                }
            }
        }
    }
}

// ---------------- gat_pre: u = fW @ aw[:512], v = fW @ aw[512:], fb dots -----
__global__ __launch_bounds__(256)
void gat_pre_kernel(const float* __restrict__ fW, const float* __restrict__ fb,
                    const float* __restrict__ aw, float* __restrict__ uv,
                    float* __restrict__ s0t0)
{
    int row = blockIdx.x * 4 + (threadIdx.x >> 6);
    int lane = threadIdx.x & 63;
    const float4* ah = (const float4*)aw;
    const float4* at = (const float4*)(aw + HH);
    if (row < 512) {
        const float4* fp = (const float4*)(fW + (size_t)row * HH);
        float du = 0.f, dv = 0.f;
#pragma unroll
        for (int l = 0; l < 2; ++l) {
            int idx = lane * 2 + l;
            float4 f = fp[idx], a = ah[idx], b = at[idx];
            du += f.x*a.x + f.y*a.y + f.z*a.z + f.w*a.w;
            dv += f.x*b.x + f.y*b.y + f.z*b.z + f.w*b.w;
        }
#pragma unroll
        for (int m = 32; m >= 1; m >>= 1) {
            du += __shfl_xor(du, m);
            dv += __shfl_xor(dv, m);
        }
        if (lane == 0) { uv[row] = du; uv[512 + row] = dv; }
    } else if (row == 512) {
        const float4* fp = (const float4*)fb;
        float du = 0.f, dv = 0.f;
#pragma unroll
        for (int l = 0; l < 2; ++l) {
            int idx = lane * 2 + l;
            float4 f = fp[idx], a = ah[idx], b = at[idx];
            du += f.x*a.x + f.y*a.y + f.z*a.z + f.w*a.w;
            dv += f.x*b.x + f.y*b.y + f.z*b.z + f.w*b.w;
        }
#pragma unroll
        for (int m = 32; m >= 1; m >>= 1) {
            du += __shfl_xor(du, m);
            dv += __shfl_xor(dv, m);
        }
        if (lane == 0) { s0t0[0] = du; s0t0[1] = dv; }
    }
}

// ---------------- rowdot2: ss[n]=Head[n].u+s0, ts[n]=Tail[n].v+t0 (bf16 rows)
__global__ __launch_bounds__(256)
void rowdot2_kernel(const short* __restrict__ Hd, const short* __restrict__ Tl,
                    const float* __restrict__ uv, const float* __restrict__ s0t0,
                    float* __restrict__ ss, float* __restrict__ ts, int N)
{
    int row = blockIdx.x * 4 + (threadIdx.x >> 6);
    int lane = threadIdx.x & 63;
    if (row >= N) return;
    short8v h = ((const short8v*)(Hd + (size_t)row * HH))[lane];
    short8v t = ((const short8v*)(Tl + (size_t)row * HH))[lane];
    const float4* up = (const float4*)uv + lane * 2;
    const float4* vp = (const float4*)(uv + HH) + lane * 2;
    float4 u0 = up[0], u1 = up[1], v0 = vp[0], v1 = vp[1];
    float a = bf2f(h[0])*u0.x + bf2f(h[1])*u0.y + bf2f(h[2])*u0.z + bf2f(h[3])*u0.w
            + bf2f(h[4])*u1.x + bf2f(h[5])*u1.y + bf2f(h[6])*u1.z + bf2f(h[7])*u1.w;
    float b = bf2f(t[0])*v0.x + bf2f(t[1])*v0.y + bf2f(t[2])*v0.z + bf2f(t[3])*v0.w
            + bf2f(t[4])*v1.x + bf2f(t[5])*v1.y + bf2f(t[6])*v1.z + bf2f(t[7])*v1.w;
#pragma unroll
    for (int m = 32; m >= 1; m >>= 1) {
        a += __shfl_xor(a, m);
        b += __shfl_xor(b, m);
    }
    if (lane == 0) { ss[row] = a + s0t0[0]; ts[row] = b + s0t0[1]; }
}

// ---------------- CSR build ----------------
__global__ __launch_bounds__(256)
void count_kernel(const int* __restrict__ src, int* __restrict__ counts, int E)
{
    int i = blockIdx.x * blockDim.x + threadIdx.x;
    if (i < E) atomicAdd(&counts[src[i]], 1);
}

__global__ __launch_bounds__(1024)
void scan_kernel(const int* __restrict__ counts, int* __restrict__ offs, int n)
{
    __shared__ int part[1024];
    const int tid = threadIdx.x;
    const int CH = (n + 1023) / 1024;
    const int base = tid * CH;
    int s = 0;
    for (int i = 0; i < CH; ++i) {
        int idx = base + i;
        if (idx < n) s += counts[idx];
    }
    part[tid] = s;
    __syncthreads();
    for (int d = 1; d < 1024; d <<= 1) {
        int v = 0;
        if (tid >= d) v = part[tid - d];
        __syncthreads();
        if (tid >= d) part[tid] += v;
        __syncthreads();
    }
    int run = (tid == 0) ? 0 : part[tid - 1];
    for (int i = 0; i < CH; ++i) {
        int idx = base + i;
        if (idx < n) { offs[idx] = run; run += counts[idx]; }
    }
    if (tid == 1023) offs[n] = run;
}

// stores the TARGET node id directly (no edge-id indirection later)
__global__ __launch_bounds__(256)
void fill_kernel(const int* __restrict__ src, const int* __restrict__ tgt,
                 int* __restrict__ cursor, int* __restrict__ tvals, int E)
{
    int i = blockIdx.x * blockDim.x + threadIdx.x;
    if (i < E) {
        int pos = atomicAdd(&cursor[src[i]], 1);
        tvals[pos] = tgt[i];
    }
}

// ---------------- fused GAT aggregate + combine (bf16 rows) -----------------
// out[s,:] = (head[s,:] + (sum_j w_j T[t_j,:]) / (sum_j w_j) + gbias) * 0.5
__global__ __launch_bounds__(256)
void gat_agg_kernel(const int* __restrict__ offs, const int* __restrict__ tvals,
                    const short* __restrict__ T,
                    const float* __restrict__ ss, const float* __restrict__ ts,
                    const float* __restrict__ ab_ptr, const short* __restrict__ head,
                    const float* __restrict__ gbias, short* __restrict__ out, int N)
{
    int s = blockIdx.x * 4 + (threadIdx.x >> 6);
    int lane = threadIdx.x & 63;
    if (s >= N) return;
    const int beg = offs[s], end = offs[s + 1];
    const float ab = ab_ptr[0];
    const float ss_s = ss[s];
    float a[8];
#pragma unroll
    for (int q = 0; q < 8; ++q) a[q] = 0.f;
    float den = 0.f;

    // 2-deep pipeline: prefetch next row while doing current FMAs
    int j = beg;
    float wq = 0.f; short8v tvq;
    if (j < end) {
        int t = tvals[j];
        wq = expf(tanhf(ss_s + ts[t] + ab));
        tvq = ((const short8v*)(T + (size_t)t * HH))[lane];
    }
    while (j < end) {
        float w = wq; short8v tv = tvq;
        ++j;
        if (j < end) {
            int t = tvals[j];
            wq = expf(tanhf(ss_s + ts[t] + ab));
            tvq = ((const short8v*)(T + (size_t)t * HH))[lane];
        }
        den += w;
#pragma unroll
        for (int q = 0; q < 8; ++q) a[q] = fmaf(w, bf2f(tv[q]), a[q]);
    }
    float inv = (den > 0.f) ? 1.f / den : 0.f;

    short8v h = ((const short8v*)(head + (size_t)s * HH))[lane];
    const float4* bp = (const float4*)gbias + lane * 2;
    float4 b0 = bp[0], b1 = bp[1];
    float bb[8] = {b0.x, b0.y, b0.z, b0.w, b1.x, b1.y, b1.z, b1.w};
    short8v o;
#pragma unroll
    for (int q = 0; q < 8; ++q)
        o[q] = f2bf((bf2f(h[q]) + a[q] * inv + bb[q]) * 0.5f);
    ((short8v*)(out + (size_t)s * HH))[lane] = o;
}

// ---------------- out = LN(tanh(Z [+ res])) * g + b, row-wise (H=512) -------
// Z bf16; res fp32 (nullable); outB bf16; outF fp32 (nullable)
__global__ __launch_bounds__(256)
void tanh_ln_kernel(const short* __restrict__ Z, const float* __restrict__ res,
                    const float* __restrict__ g, const float* __restrict__ bta,
                    short* __restrict__ outB, float* __restrict__ outF, int N)
{
    int row = blockIdx.x * 4 + (threadIdx.x >> 6);
    int lane = threadIdx.x & 63;
    if (row >= N) return;
    short8v zv = ((const short8v*)(Z + (size_t)row * HH))[lane];
    float v[8];
    float sum = 0.f, sum2 = 0.f;
    float rr[8];
    if (res) {
        const float4* rp = (const float4*)(res + (size_t)row * HH) + lane * 2;
        float4 r0 = rp[0], r1 = rp[1];
        rr[0]=r0.x; rr[1]=r0.y; rr[2]=r0.z; rr[3]=r0.w;
        rr[4]=r1.x; rr[5]=r1.y; rr[6]=r1.z; rr[7]=r1.w;
    } else {
#pragma unroll
        for (int q = 0; q < 8; ++q) rr[q] = 0.f;
    }
#pragma unroll
    for (int q = 0; q < 8; ++q) {
        float t = tanhf(bf2f(zv[q]) + rr[q]);
        v[q] = t;
        sum += t;
        sum2 = fmaf(t, t, sum2);
    }
#pragma unroll
    for (int m = 32; m >= 1; m >>= 1) {
        sum  += __shfl_xor(sum, m);
        sum2 += __shfl_xor(sum2, m);
    }
    float mu  = sum * (1.f/HH);
    float var = sum2 * (1.f/HH) - mu*mu;
    float rs  = rsqrtf(var + 1e-5f);
    const float4* gp = (const float4*)g + lane * 2;
    const float4* bp = (const float4*)bta + lane * 2;
    float4 g0 = gp[0], g1 = gp[1], c0 = bp[0], c1 = bp[1];
    float gg[8] = {g0.x, g0.y, g0.z, g0.w, g1.x, g1.y, g1.z, g1.w};
    float cc[8] = {c0.x, c0.y, c0.z, c0.w, c1.x, c1.y, c1.z, c1.w};
    float o[8];
#pragma unroll
    for (int q = 0; q < 8; ++q) o[q] = (v[q]-mu)*rs*gg[q] + cc[q];
    short8v ob;
#pragma unroll
    for (int q = 0; q < 8; ++q) ob[q] = f2bf(o[q]);
    ((short8v*)(outB + (size_t)row * HH))[lane] = ob;
    if (outF) {
        float4* op = (float4*)(outF + (size_t)row * HH) + lane * 2;
        op[0] = make_float4(o[0], o[1], o[2], o[3]);
        op[1] = make_float4(o[4], o[5], o[6], o[7]);
    }
}

// ---------------- out[n] = sigmoid(X[n,:].Wc + bc), X bf16 -------------------
__global__ __launch_bounds__(256)
void cls_kernel(const short* __restrict__ X, const float* __restrict__ Wc,
                const float* __restrict__ bc, float* __restrict__ out, int N)
{
    int row = blockIdx.x * 4 + (threadIdx.x >> 6);
    int lane = threadIdx.x & 63;
    if (row >= N) return;
    short8v x = ((const short8v*)(X + (size_t)row * HH))[lane];
    const float4* wp = (const float4*)Wc + lane * 2;
    float4 w0 = wp[0], w1 = wp[1];
    float acc = bf2f(x[0])*w0.x + bf2f(x[1])*w0.y + bf2f(x[2])*w0.z + bf2f(x[3])*w0.w
              + bf2f(x[4])*w1.x + bf2f(x[5])*w1.y + bf2f(x[6])*w1.z + bf2f(x[7])*w1.w;
#pragma unroll
    for (int m = 32; m >= 1; m >>= 1) acc += __shfl_xor(acc, m);
    if (lane == 0) out[row] = 1.f / (1.f + expf(-(acc + bc[0])));
}

extern "C" void kernel_launch(void* const* d_in, const int* in_sizes, int n_in,
                              void* d_out, int out_size, void* d_ws, size_t ws_size,
                              hipStream_t stream)
{
    (void)in_sizes; (void)n_in; (void)out_size; (void)ws_size;
    const int N = NN, E = NE, H = HH;
    const size_t NHf = (size_t)N * H;

    const float* fu0 = (const float*)d_in[0];
    const float* fi1 = (const float*)d_in[3];
    const float* fu2 = (const float*)d_in[4];
    const int* eUI0 = (const int*)d_in[6];
    const int* eIU1 = (const int*)d_in[9];
    const float* Wu  = (const float*)d_in[10];
    const float* bu  = (const float*)d_in[11];
    const float* Wi  = (const float*)d_in[12];
    const float* bi  = (const float*)d_in[13];
    const float* gfW = (const float*)d_in[14];
    const float* gfb = (const float*)d_in[15];
    const float* gaw = (const float*)d_in[16];
    const float* gab = (const float*)d_in[17];
    const float* gbias = (const float*)d_in[18];
    const float* prW = (const float*)d_in[19];
    const float* prb = (const float*)d_in[20];
    const float* dW  = (const float*)d_in[21];
    const float* db  = (const float*)d_in[22];
    const float* dlg = (const float*)d_in[23];
    const float* dlb = (const float*)d_in[24];
    const float* rlg = (const float*)d_in[25];
    const float* rlb = (const float*)d_in[26];
    const float* cW  = (const float*)d_in[27];
    const float* cb  = (const float*)d_in[28];

    // fp32 region
    float* B5   = (float*)d_ws;      // residual sc (only fp32 activation)
    float* ssb  = B5 + NHf;          // [N]
    float* tsb  = ssb + N;           // [N]
    float* uv   = tsb + N;           // [1024]
    float* s0t0 = uv + 1024;         // [2] (+pad)
    int* counts = (int*)(s0t0 + 4);  // [N]
    int* offs   = counts + N;        // [N+1]
    int* cursor = offs + N + 1;      // [N]
    int* tvals  = cursor + N;        // [E] CSR-ordered target ids
    size_t boff = (size_t)((char*)(tvals + E) - (char*)d_ws);
    boff = (boff + 15) & ~(size_t)15;
    // bf16 activations (with lifetime-based reuse)
    short* S0    = (short*)((char*)d_ws + boff); // raw feat: fu2, later fu0
    short* XI1   = S0 + NHf;                     // N*256 raw item feat
    short* SU    = XI1 + NHf / 2;                // su ; later ZB (dnn gemm out)
    short* HI    = SU + NHf;                     // hi ; later HU0
    short* SINEW = HI + NHf;                     // si_new ; later XB (dnn stream)
    short* T4    = SINEW + NHf;                  // gat tail transform
    short* SUF   = T4 + NHf;                     // su_final
    short* WTu   = SUF + NHf;
    short* WTi   = WTu + 512 * 512;
    short* WTg0  = WTi + 512 * 256;
    short* WTg1  = WTg0 + 512 * 512;
    short* WTpr  = WTg1 + 512 * 512;
    short* WTd   = WTpr + 512 * 512;             // 4 x 512*512
    short* XU0 = S0;      // alias after su computed
    short* HU0 = HI;      // alias after GAT1 done
    short* XB  = SINEW;   // alias after GAT0 done
    short* ZB  = SU;      // alias after GAT1's rowdot/MLIN done

    // ---- weight pre-pass: transpose + bf16 ----
    auto WTR = [&](const float* src, short* dst, int K) {
        hipLaunchKernelGGL(wtr_kernel, dim3(16, K / 32), dim3(32, 8), 0, stream,
                           src, dst, K, 512);
    };
    WTR(Wu, WTu, 512);
    WTR(Wi, WTi, 256);
    WTR(gfW, WTg0, 512);
    WTR(gfW + (size_t)H * H, WTg1, 512);
    WTR(prW, WTpr, 512);
    for (int k = 0; k < 4; ++k)
        WTR(dW + (size_t)k * H * H, WTd + (size_t)k * 512 * 512, 512);

    // ---- raw feature converts ----
    auto F2B = [&](const float* src, short* dst, size_t n) {
        int n8 = (int)(n / 8);
        hipLaunchKernelGGL(f2b_kernel, dim3((n8 + 255) / 256), dim3(256), 0, stream,
                           src, dst, n8);
    };

    const int nby = (N + 127) / 128;
    const int nwg = nby * 4;
    auto MLIN = [&](const short* X, const short* WT, const float* b,
                    float* oF, short* oB, int K) {
        hipLaunchKernelGGL(mfma_lin, dim3(nwg), dim3(256), 0, stream,
                           X, WT, b, oF, oB, N, K);
    };
    const int rgrid = (N + 3) / 4;
    const int egrid = (E + 255) / 256;

    auto GAT = [&](int r, const short* headB, const short* tailB, const short* WTg,
                   const int* edges, short* outB) {
        hipLaunchKernelGGL(gat_pre_kernel, dim3(129), dim3(256), 0, stream,
                           gfW + (size_t)r * H * H, gfb + r * H, gaw + (size_t)r * 2 * H,
                           uv, s0t0);
        MLIN(tailB, WTg, gfb + r * H, nullptr, T4, 512);
        hipLaunchKernelGGL(rowdot2_kernel, dim3(rgrid), dim3(256), 0, stream,
                           headB, tailB, uv, s0t0, ssb, tsb, N);
        hipMemsetAsync(counts, 0, N * sizeof(int), stream);
        hipLaunchKernelGGL(count_kernel, dim3(egrid), dim3(256), 0, stream,
                           edges, counts, E);
        hipLaunchKernelGGL(scan_kernel, dim3(1), dim3(1024), 0, stream,
                           counts, offs, N);
        hipMemcpyAsync(cursor, offs, N * sizeof(int), hipMemcpyDeviceToDevice, stream);
        hipLaunchKernelGGL(fill_kernel, dim3(egrid), dim3(256), 0, stream,
                           edges, edges + E, cursor, tvals, E);
        hipLaunchKernelGGL(gat_agg_kernel, dim3(rgrid), dim3(256), 0, stream,
                           offs, tvals, T4, ssb, tsb, gab + r,
                           headB, gbias + (size_t)r * H, outB, N);
    };

    // hop-2 / hop-1 live transforms
    F2B(fu2, S0, NHf);
    F2B(fi1, XI1, NHf / 2);
    MLIN(S0, WTu, bu, nullptr, SU, 512);     // su
    MLIN(XI1, WTi, bi, nullptr, HI, 256);    // hi
    GAT(1, HI, SU, WTg1, eIU1, SINEW);       // si_new
    F2B(fu0, XU0, NHf);                      // reuse S0
    MLIN(XU0, WTu, bu, nullptr, HU0, 512);   // hu0 (reuses HI)
    GAT(0, HU0, SINEW, WTg0, eUI0, SUF);     // su_final

    // Res_DNN head: x = prep(su_final); dual-write fp32 sc + bf16 stream
    MLIN(SUF, WTpr, prb, B5, XB, 512);
    for (int r = 0; r < 2; ++r) {
        for (int d = 0; d < 2; ++d) {
            MLIN(XB, WTd + (size_t)(r * 2 + d) * 512 * 512, db + (r * 2 + d) * H,
                 nullptr, ZB, 512);
            hipLaunchKernelGGL(tanh_ln_kernel, dim3(rgrid), dim3(256), 0, stream,
                               ZB, (const float*)nullptr, dlg + (r * 2 + d) * H,
                               dlb + (r * 2 + d) * H, XB, (float*)nullptr, N);
        }
        // x = LN(tanh(sc + x)); for r=0 also refresh sc (fp32) for next block
        hipLaunchKernelGGL(tanh_ln_kernel, dim3(rgrid), dim3(256), 0, stream,
                           XB, B5, rlg + r * H, rlb + r * H, XB,
                           (r == 0) ? B5 : (float*)nullptr, N);
    }
    hipLaunchKernelGGL(cls_kernel, dim3(rgrid), dim3(256), 0, stream,
                       XB, cW, cb, (float*)d_out, N);
}

// Round 5
// 594.747 us; speedup vs baseline: 12.4094x; 1.0767x over previous
//
#include <hip/hip_runtime.h>
#include <math.h>

#define NN 20000
#define NE 200000
#define HH 512

typedef __attribute__((ext_vector_type(8))) short short8v;
typedef __attribute__((ext_vector_type(4))) float f32x4;

__device__ inline short f2bf(float f) {
    union { float f; unsigned u; } v; v.f = f;
    unsigned r = (v.u + 0x7fffu + ((v.u >> 16) & 1u)) >> 16;
    return (short)r;
}
__device__ inline float bf2f(short s) {
    union { unsigned u; float f; } v;
    v.u = ((unsigned)(unsigned short)s) << 16;
    return v.f;
}

// direct global->LDS DMA, 16B per lane; lds dest must be wave-uniform base
__device__ inline void gload_lds16(const void* g, void* l) {
    __builtin_amdgcn_global_load_lds(
        (const __attribute__((address_space(1))) void*)g,
        (__attribute__((address_space(3))) void*)l, 16, 0, 0);
}

// ---------------- fp32 -> bf16 bulk convert (8 elems/thread) ----------------
__global__ __launch_bounds__(256)
void f2b_kernel(const float* __restrict__ src, short* __restrict__ dst, int n8)
{
    int i = blockIdx.x * 256 + threadIdx.x;
    if (i >= n8) return;
    const float4* p = (const float4*)src + (size_t)i * 2;
    float4 a = p[0], b = p[1];
    short8v s;
    s[0] = f2bf(a.x); s[1] = f2bf(a.y); s[2] = f2bf(a.z); s[3] = f2bf(a.w);
    s[4] = f2bf(b.x); s[5] = f2bf(b.y); s[6] = f2bf(b.z); s[7] = f2bf(b.w);
    ((short8v*)dst)[i] = s;
}

// ---------------- weight transpose + bf16 convert: dst[n][k] = src[k][n] ----
__global__ __launch_bounds__(256)
void wtr_kernel(const float* __restrict__ src, short* __restrict__ dst,
                int K, int Ncols)
{
    __shared__ float t[32][33];
    int bx = blockIdx.x * 32;
    int by = blockIdx.y * 32;
    int tx = threadIdx.x, ty = threadIdx.y;
    for (int i = ty; i < 32; i += 8)
        t[i][tx] = src[(size_t)(by + i) * Ncols + bx + tx];
    __syncthreads();
    for (int i = ty; i < 32; i += 8)
        dst[(size_t)(bx + i) * K + by + tx] = f2bf(t[tx][i]);
}

// ---------------- MFMA GEMM: out[M,512] = X[M,K](bf16) @ WT[512,K](bf16)^T + b
// 128x128 tile, BK=32, 4 waves (2x2), wave 64x64 (4x4 frags of 16x16x32).
// Staging via global_load_lds (linear LDS dest, chunk-XOR pre-swizzled source).
__global__ __launch_bounds__(256)
void mfma_lin(const short* __restrict__ X, const short* __restrict__ WT,
              const float* __restrict__ bias, float* __restrict__ outF,
              short* __restrict__ outB, int M, int K)
{
    __shared__ short8v As[2][512];   // [row 0..127][chunk-slot 0..3]
    __shared__ short8v Bs[2][512];

    const int tid = threadIdx.x;
    const int lane = tid & 63;
    const int w = tid >> 6;

    // XCD-chunked bijective swizzle over 1D grid
    const int nby = (M + 127) >> 7;
    const int nwg = nby << 2;
    const int q = nwg >> 3, r = nwg & 7;
    int id = blockIdx.x;
    int xcd = id & 7, wi = id >> 3;
    int wgid = (xcd < r ? xcd * (q + 1) : r * (q + 1) + (xcd - r) * q) + wi;
    const int col0 = (wgid & 3) * 128;
    const int row0 = (wgid >> 2) * 128;

    const int wr = (w >> 1) * 64;
    const int wc = (w & 1) * 64;

    // staging geometry: this wave covers slots p in [w*128, w*128+128)
    // slot p -> lds row = p>>2, chunk-slot = p&3; data = logical chunk (slot^swz(row))
    int sp0 = w * 128 + lane;           // q=0 slot
    int sp1 = sp0 + 64;                 // q=1 slot
    int r0_ = sp0 >> 2, r1_ = sp1 >> 2;
    int c0_ = (sp0 & 3) ^ ((r0_ >> 1) & 3);
    int c1_ = (sp1 & 3) ^ ((r1_ >> 1) & 3);
    int ga0 = row0 + r0_; if (ga0 >= M) ga0 = M - 1;   // clamp: OOB rows masked at store
    int ga1 = row0 + r1_; if (ga1 >= M) ga1 = M - 1;
    const short* ag0 = X + (size_t)ga0 * K + c0_ * 8;
    const short* ag1 = X + (size_t)ga1 * K + c1_ * 8;
    const short* bg0 = WT + (size_t)(col0 + r0_) * K + c0_ * 8;
    const short* bg1 = WT + (size_t)(col0 + r1_) * K + c1_ * 8;

    // fragment read indices (same chunk-XOR swizzle)
    int ar[4], br[4];
#pragma unroll
    for (int i = 0; i < 4; ++i) {
        int rr = wr + i * 16 + (lane & 15);
        ar[i] = rr * 4 + ((lane >> 4) ^ ((rr >> 1) & 3));
        int nn = wc + i * 16 + (lane & 15);
        br[i] = nn * 4 + ((lane >> 4) ^ ((nn >> 1) & 3));
    }

    f32x4 acc[4][4];
#pragma unroll
    for (int i = 0; i < 4; ++i)
#pragma unroll
        for (int j = 0; j < 4; ++j)
            acc[i][j] = (f32x4){0.f, 0.f, 0.f, 0.f};

    auto stage = [&](int buf, int kk) {
        gload_lds16(ag0 + kk, &As[buf][sp0 & ~63]);
        gload_lds16(ag1 + kk, &As[buf][sp1 & ~63]);
        gload_lds16(bg0 + kk, &Bs[buf][sp0 & ~63]);
        gload_lds16(bg1 + kk, &Bs[buf][sp1 & ~63]);
    };

    const int nt = K >> 5;
    stage(0, 0);
    __syncthreads();
    int cur = 0;
    for (int t = 0; t < nt; ++t) {
        if (t + 1 < nt) stage(cur ^ 1, (t + 1) * 32);
        short8v af[4], bf[4];
#pragma unroll
        for (int i = 0; i < 4; ++i) af[i] = As[cur][ar[i]];
#pragma unroll
        for (int j = 0; j < 4; ++j) bf[j] = Bs[cur][br[j]];
#pragma unroll
        for (int i = 0; i < 4; ++i)
#pragma unroll
            for (int j = 0; j < 4; ++j)
                acc[i][j] = __builtin_amdgcn_mfma_f32_16x16x32_bf16(af[i], bf[j], acc[i][j], 0, 0, 0);
        __syncthreads();
        cur ^= 1;
    }

    float bj[4];
#pragma unroll
    for (int j = 0; j < 4; ++j)
        bj[j] = bias[col0 + wc + j * 16 + (lane & 15)];
#pragma unroll
    for (int i = 0; i < 4; ++i) {
#pragma unroll
        for (int rr = 0; rr < 4; ++rr) {
            int row = row0 + wr + i * 16 + (lane >> 4) * 4 + rr;
            if (row < M) {
                size_t base = (size_t)row * HH + col0 + wc + (lane & 15);
                if (outF) {
                    float* op = outF + base;
#pragma unroll
                    for (int j = 0; j < 4; ++j) op[j * 16] = acc[i][j][rr] + bj[j];
                }
                if (outB) {
                    short* op = outB + base;
#pragma unroll
                    for (int j = 0; j < 4; ++j) op[j * 16] = f2bf(acc[i][j][rr] + bj[j]);
                }
            }
        }
    }
}

// ---------------- gat_pre: u = fW @ aw[:512], v = fW @ aw[512:], fb dots -----
__global__ __launch_bounds__(256)
void gat_pre_kernel(const float* __restrict__ fW, const float* __restrict__ fb,
                    const float* __restrict__ aw, float* __restrict__ uv,
                    float* __restrict__ s0t0)
{
    int row = blockIdx.x * 4 + (threadIdx.x >> 6);
    int lane = threadIdx.x & 63;
    const float4* ah = (const float4*)aw;
    const float4* at = (const float4*)(aw + HH);
    const float4* fp;
    if (row < 512)      fp = (const float4*)(fW + (size_t)row * HH);
    else if (row == 512) fp = (const float4*)fb;
    else return;
    float du = 0.f, dv = 0.f;
#pragma unroll
    for (int l = 0; l < 2; ++l) {
        int idx = lane * 2 + l;
        float4 f = fp[idx], a = ah[idx], b = at[idx];
        du += f.x*a.x + f.y*a.y + f.z*a.z + f.w*a.w;
        dv += f.x*b.x + f.y*b.y + f.z*b.z + f.w*b.w;
    }
#pragma unroll
    for (int m = 32; m >= 1; m >>= 1) {
        du += __shfl_xor(du, m);
        dv += __shfl_xor(dv, m);
    }
    if (lane == 0) {
        if (row < 512) { uv[row] = du; uv[512 + row] = dv; }
        else           { s0t0[0] = du; s0t0[1] = dv; }
    }
}

// ---------------- rowdot2: ss[n]=Head[n].u+s0, ts[n]=Tail[n].v+t0 (bf16 rows)
__global__ __launch_bounds__(256)
void rowdot2_kernel(const short* __restrict__ Hd, const short* __restrict__ Tl,
                    const float* __restrict__ uv, const float* __restrict__ s0t0,
                    float* __restrict__ ss, float* __restrict__ ts, int N)
{
    int row = blockIdx.x * 4 + (threadIdx.x >> 6);
    int lane = threadIdx.x & 63;
    if (row >= N) return;
    short8v h = ((const short8v*)(Hd + (size_t)row * HH))[lane];
    short8v t = ((const short8v*)(Tl + (size_t)row * HH))[lane];
    const float4* up = (const float4*)uv + lane * 2;
    const float4* vp = (const float4*)(uv + HH) + lane * 2;
    float4 u0 = up[0], u1 = up[1], v0 = vp[0], v1 = vp[1];
    float a = bf2f(h[0])*u0.x + bf2f(h[1])*u0.y + bf2f(h[2])*u0.z + bf2f(h[3])*u0.w
            + bf2f(h[4])*u1.x + bf2f(h[5])*u1.y + bf2f(h[6])*u1.z + bf2f(h[7])*u1.w;
    float b = bf2f(t[0])*v0.x + bf2f(t[1])*v0.y + bf2f(t[2])*v0.z + bf2f(t[3])*v0.w
            + bf2f(t[4])*v1.x + bf2f(t[5])*v1.y + bf2f(t[6])*v1.z + bf2f(t[7])*v1.w;
#pragma unroll
    for (int m = 32; m >= 1; m >>= 1) {
        a += __shfl_xor(a, m);
        b += __shfl_xor(b, m);
    }
    if (lane == 0) { ss[row] = a + s0t0[0]; ts[row] = b + s0t0[1]; }
}

// ---------------- CSR build (both relations, hoisted) ----------------
__global__ __launch_bounds__(256)
void count2_kernel(const int* __restrict__ s0, const int* __restrict__ s1,
                   int* __restrict__ c0, int* __restrict__ c1, int E)
{
    int i = blockIdx.x * blockDim.x + threadIdx.x;
    if (i < E) atomicAdd(&c0[s0[i]], 1);
    else if (i < 2 * E) atomicAdd(&c1[s1[i - E]], 1);
}

// exclusive scan; blockIdx 0 -> {c0->o0,u0}, 1 -> {c1->o1,u1}
__global__ __launch_bounds__(1024)
void scan2_kernel(const int* __restrict__ c0, const int* __restrict__ c1,
                  int* __restrict__ o0, int* __restrict__ o1,
                  int* __restrict__ u0, int* __restrict__ u1, int n)
{
    const int* counts = blockIdx.x ? c1 : c0;
    int* offs = blockIdx.x ? o1 : o0;
    int* curs = blockIdx.x ? u1 : u0;
    __shared__ int part[1024];
    const int tid = threadIdx.x;
    const int CH = (n + 1023) / 1024;
    const int base = tid * CH;
    int s = 0;
    for (int i = 0; i < CH; ++i) {
        int idx = base + i;
        if (idx < n) s += counts[idx];
    }
    part[tid] = s;
    __syncthreads();
    for (int d = 1; d < 1024; d <<= 1) {
        int v = 0;
        if (tid >= d) v = part[tid - d];
        __syncthreads();
        if (tid >= d) part[tid] += v;
        __syncthreads();
    }
    int run = (tid == 0) ? 0 : part[tid - 1];
    for (int i = 0; i < CH; ++i) {
        int idx = base + i;
        if (idx < n) { offs[idx] = run; curs[idx] = run; run += counts[idx]; }
    }
    if (tid == 1023) offs[n] = run;
}

// fill CSR with target ids AND precomputed edge weights
__global__ __launch_bounds__(256)
void fill_kernel(const int* __restrict__ src, const int* __restrict__ tgt,
                 const float* __restrict__ ss, const float* __restrict__ ts,
                 const float* __restrict__ ab_ptr, int* __restrict__ cursor,
                 int* __restrict__ tvals, float* __restrict__ wv, int E)
{
    int i = blockIdx.x * blockDim.x + threadIdx.x;
    if (i >= E) return;
    int s = src[i], t = tgt[i];
    int pos = atomicAdd(&cursor[s], 1);
    tvals[pos] = t;
    wv[pos] = expf(tanhf(ss[s] + ts[t] + ab_ptr[0]));
}

// ---------------- fused GAT aggregate + combine (bf16 rows) -----------------
// out[s,:] = (head[s,:] + (sum_j w_j T[t_j,:]) / (sum_j w_j) + gbias) * 0.5
__global__ __launch_bounds__(256)
void gat_agg_kernel(const int* __restrict__ offs, const int* __restrict__ tvals,
                    const float* __restrict__ wv, const short* __restrict__ T,
                    const short* __restrict__ head, const float* __restrict__ gbias,
                    short* __restrict__ out, int N)
{
    int s = blockIdx.x * 4 + (threadIdx.x >> 6);
    int lane = threadIdx.x & 63;
    if (s >= N) return;
    const int beg = offs[s], end = offs[s + 1];
    float a[8];
#pragma unroll
    for (int q = 0; q < 8; ++q) a[q] = 0.f;
    float den = 0.f;

    // 2-deep pipeline: prefetch next (w, row) while doing current FMAs
    int j = beg;
    float wq = 0.f; short8v tvq;
    if (j < end) {
        wq = wv[j];
        tvq = ((const short8v*)(T + (size_t)tvals[j] * HH))[lane];
    }
    while (j < end) {
        float w = wq; short8v tv = tvq;
        ++j;
        if (j < end) {
            wq = wv[j];
            tvq = ((const short8v*)(T + (size_t)tvals[j] * HH))[lane];
        }
        den += w;
#pragma unroll
        for (int q = 0; q < 8; ++q) a[q] = fmaf(w, bf2f(tv[q]), a[q]);
    }
    float inv = (den > 0.f) ? 1.f / den : 0.f;

    short8v h = ((const short8v*)(head + (size_t)s * HH))[lane];
    const float4* bp = (const float4*)gbias + lane * 2;
    float4 b0 = bp[0], b1 = bp[1];
    float bb[8] = {b0.x, b0.y, b0.z, b0.w, b1.x, b1.y, b1.z, b1.w};
    short8v o;
#pragma unroll
    for (int q = 0; q < 8; ++q)
        o[q] = f2bf((bf2f(h[q]) + a[q] * inv + bb[q]) * 0.5f);
    ((short8v*)(out + (size_t)s * HH))[lane] = o;
}

// ---------------- out = LN(tanh(Z [+ res])) * g + b, row-wise (H=512) -------
// Z bf16; res fp32 (nullable); outB bf16 (nullable); outF fp32 (nullable);
// optional fused classifier: outCls[row] = sigmoid(out_row . cW + cb)
__global__ __launch_bounds__(256)
void tanh_ln_kernel(const short* __restrict__ Z, const float* __restrict__ res,
                    const float* __restrict__ g, const float* __restrict__ bta,
                    short* __restrict__ outB, float* __restrict__ outF,
                    const float* __restrict__ cWp, const float* __restrict__ cbp,
                    float* __restrict__ outCls, int N)
{
    int row = blockIdx.x * 4 + (threadIdx.x >> 6);
    int lane = threadIdx.x & 63;
    if (row >= N) return;
    short8v zv = ((const short8v*)(Z + (size_t)row * HH))[lane];
    float v[8];
    float sum = 0.f, sum2 = 0.f;
    float rr[8];
    if (res) {
        const float4* rp = (const float4*)(res + (size_t)row * HH) + lane * 2;
        float4 r0 = rp[0], r1 = rp[1];
        rr[0]=r0.x; rr[1]=r0.y; rr[2]=r0.z; rr[3]=r0.w;
        rr[4]=r1.x; rr[5]=r1.y; rr[6]=r1.z; rr[7]=r1.w;
    } else {
#pragma unroll
        for (int q = 0; q < 8; ++q) rr[q] = 0.f;
    }
#pragma unroll
    for (int q = 0; q < 8; ++q) {
        float t = tanhf(bf2f(zv[q]) + rr[q]);
        v[q] = t;
        sum += t;
        sum2 = fmaf(t, t, sum2);
    }
#pragma unroll
    for (int m = 32; m >= 1; m >>= 1) {
        sum  += __shfl_xor(sum, m);
        sum2 += __shfl_xor(sum2, m);
    }
    float mu  = sum * (1.f/HH);
    float var = sum2 * (1.f/HH) - mu*mu;
    float rs  = rsqrtf(var + 1e-5f);
    const float4* gp = (const float4*)g + lane * 2;
    const float4* bp = (const float4*)bta + lane * 2;
    float4 g0 = gp[0], g1 = gp[1], c0 = bp[0], c1 = bp[1];
    float gg[8] = {g0.x, g0.y, g0.z, g0.w, g1.x, g1.y, g1.z, g1.w};
    float cc[8] = {c0.x, c0.y, c0.z, c0.w, c1.x, c1.y, c1.z, c1.w};
    float o[8];
#pragma unroll
    for (int q = 0; q < 8; ++q) o[q] = (v[q]-mu)*rs*gg[q] + cc[q];
    if (outB) {
        short8v ob;
#pragma unroll
        for (int q = 0; q < 8; ++q) ob[q] = f2bf(o[q]);
        ((short8v*)(outB + (size_t)row * HH))[lane] = ob;
    }
    if (outF) {
        float4* op = (float4*)(outF + (size_t)row * HH) + lane * 2;
        op[0] = make_float4(o[0], o[1], o[2], o[3]);
        op[1] = make_float4(o[4], o[5], o[6], o[7]);
    }
    if (cWp) {
        const float4* wp = (const float4*)cWp + lane * 2;
        float4 w0 = wp[0], w1 = wp[1];
        float acc = o[0]*w0.x + o[1]*w0.y + o[2]*w0.z + o[3]*w0.w
                  + o[4]*w1.x + o[5]*w1.y + o[6]*w1.z + o[7]*w1.w;
#pragma unroll
        for (int m = 32; m >= 1; m >>= 1) acc += __shfl_xor(acc, m);
        if (lane == 0) outCls[row] = 1.f / (1.f + expf(-(acc + cbp[0])));
    }
}

extern "C" void kernel_launch(void* const* d_in, const int* in_sizes, int n_in,
                              void* d_out, int out_size, void* d_ws, size_t ws_size,
                              hipStream_t stream)
{
    (void)in_sizes; (void)n_in; (void)out_size; (void)ws_size;
    const int N = NN, E = NE, H = HH;
    const size_t NHf = (size_t)N * H;

    const float* fu0 = (const float*)d_in[0];
    const float* fi1 = (const float*)d_in[3];
    const float* fu2 = (const float*)d_in[4];
    const int* eUI0 = (const int*)d_in[6];
    const int* eIU1 = (const int*)d_in[9];
    const float* Wu  = (const float*)d_in[10];
    const float* bu  = (const float*)d_in[11];
    const float* Wi  = (const float*)d_in[12];
    const float* bi  = (const float*)d_in[13];
    const float* gfW = (const float*)d_in[14];
    const float* gfb = (const float*)d_in[15];
    const float* gaw = (const float*)d_in[16];
    const float* gab = (const float*)d_in[17];
    const float* gbias = (const float*)d_in[18];
    const float* prW = (const float*)d_in[19];
    const float* prb = (const float*)d_in[20];
    const float* dW  = (const float*)d_in[21];
    const float* db  = (const float*)d_in[22];
    const float* dlg = (const float*)d_in[23];
    const float* dlb = (const float*)d_in[24];
    const float* rlg = (const float*)d_in[25];
    const float* rlb = (const float*)d_in[26];
    const float* cW  = (const float*)d_in[27];
    const float* cb  = (const float*)d_in[28];

    // fp32 region
    float* B5   = (float*)d_ws;      // residual sc (fp32)
    float* ssb  = B5 + NHf;          // [N]
    float* tsb  = ssb + N;           // [N]
    float* uv   = tsb + N;           // [1024]
    float* s0t0 = uv + 1024;         // [2] (+pad)
    float* wvb  = s0t0 + 4;          // [E] CSR-ordered edge weights
    int* counts0 = (int*)(wvb + E);  // [N]
    int* counts1 = counts0 + N;      // [N]
    int* offs0   = counts1 + N;      // [N+1]
    int* offs1   = offs0 + N + 1;    // [N+1]
    int* cur0    = offs1 + N + 1;    // [N]
    int* cur1    = cur0 + N;         // [N]
    int* tvals   = cur1 + N;         // [E] CSR-ordered target ids
    size_t boff = (size_t)((char*)(tvals + E) - (char*)d_ws);
    boff = (boff + 15) & ~(size_t)15;
    // bf16 activations (lifetime-based reuse)
    short* S0    = (short*)((char*)d_ws + boff); // raw feat: fu2, later fu0
    short* XI1   = S0 + NHf;                     // N*256 raw item feat
    short* SU    = XI1 + NHf / 2;                // su ; later ZB
    short* HI    = SU + NHf;                     // hi ; later HU0
    short* SINEW = HI + NHf;                     // si_new ; later XB
    short* T4    = SINEW + NHf;                  // gat tail transform
    short* SUF   = T4 + NHf;                     // su_final
    short* WTu   = SUF + NHf;
    short* WTi   = WTu + 512 * 512;
    short* WTg0  = WTi + 512 * 256;
    short* WTg1  = WTg0 + 512 * 512;
    short* WTpr  = WTg1 + 512 * 512;
    short* WTd   = WTpr + 512 * 512;             // 4 x 512*512
    short* XU0 = S0;
    short* HU0 = HI;
    short* XB  = SINEW;
    short* ZB  = SU;

    // ---- weight pre-pass ----
    auto WTR = [&](const float* src, short* dst, int K) {
        hipLaunchKernelGGL(wtr_kernel, dim3(16, K / 32), dim3(32, 8), 0, stream,
                           src, dst, K, 512);
    };
    WTR(Wu, WTu, 512);
    WTR(Wi, WTi, 256);
    WTR(gfW, WTg0, 512);
    WTR(gfW + (size_t)H * H, WTg1, 512);
    WTR(prW, WTpr, 512);
    for (int k = 0; k < 4; ++k)
        WTR(dW + (size_t)k * H * H, WTd + (size_t)k * 512 * 512, 512);

    auto F2B = [&](const float* src, short* dst, size_t n) {
        int n8 = (int)(n / 8);
        hipLaunchKernelGGL(f2b_kernel, dim3((n8 + 255) / 256), dim3(256), 0, stream,
                           src, dst, n8);
    };

    // ---- CSR build (edges are pure inputs; hoisted, both relations) ----
    hipMemsetAsync(counts0, 0, 2 * N * sizeof(int), stream);
    hipLaunchKernelGGL(count2_kernel, dim3((2 * E + 255) / 256), dim3(256), 0, stream,
                       eUI0, eIU1, counts0, counts1, E);
    hipLaunchKernelGGL(scan2_kernel, dim3(2), dim3(1024), 0, stream,
                       counts0, counts1, offs0, offs1, cur0, cur1, N);

    const int nby = (N + 127) / 128;
    const int nwg = nby * 4;
    auto MLIN = [&](const short* X, const short* WT, const float* b,
                    float* oF, short* oB, int K) {
        hipLaunchKernelGGL(mfma_lin, dim3(nwg), dim3(256), 0, stream,
                           X, WT, b, oF, oB, N, K);
    };
    const int rgrid = (N + 3) / 4;
    const int egrid = (E + 255) / 256;

    auto GAT = [&](int r, const short* headB, const short* tailB, const short* WTg,
                   const int* edges, int* offs, int* curs, short* outB) {
        hipLaunchKernelGGL(gat_pre_kernel, dim3(130), dim3(256), 0, stream,
                           gfW + (size_t)r * H * H, gfb + r * H, gaw + (size_t)r * 2 * H,
                           uv, s0t0);
        MLIN(tailB, WTg, gfb + r * H, nullptr, T4, 512);
        hipLaunchKernelGGL(rowdot2_kernel, dim3(rgrid), dim3(256), 0, stream,
                           headB, tailB, uv, s0t0, ssb, tsb, N);
        hipLaunchKernelGGL(fill_kernel, dim3(egrid), dim3(256), 0, stream,
                           edges, edges + E, ssb, tsb, gab + r, curs, tvals, wvb, E);
        hipLaunchKernelGGL(gat_agg_kernel, dim3(rgrid), dim3(256), 0, stream,
                           offs, tvals, wvb, T4, headB, gbias + (size_t)r * H, outB, N);
    };

    // hop-2 / hop-1 live transforms
    F2B(fu2, S0, NHf);
    F2B(fi1, XI1, NHf / 2);
    MLIN(S0, WTu, bu, nullptr, SU, 512);              // su
    MLIN(XI1, WTi, bi, nullptr, HI, 256);             // hi
    GAT(1, HI, SU, WTg1, eIU1, offs1, cur1, SINEW);   // si_new
    F2B(fu0, XU0, NHf);
    MLIN(XU0, WTu, bu, nullptr, HU0, 512);            // hu0
    GAT(0, HU0, SINEW, WTg0, eUI0, offs0, cur0, SUF); // su_final

    // Res_DNN head
    MLIN(SUF, WTpr, prb, B5, XB, 512);
    for (int r = 0; r < 2; ++r) {
        for (int d = 0; d < 2; ++d) {
            MLIN(XB, WTd + (size_t)(r * 2 + d) * 512 * 512, db + (r * 2 + d) * H,
                 nullptr, ZB, 512);
            hipLaunchKernelGGL(tanh_ln_kernel, dim3(rgrid), dim3(256), 0, stream,
                               ZB, (const float*)nullptr, dlg + (r * 2 + d) * H,
                               dlb + (r * 2 + d) * H, XB, (float*)nullptr,
                               (const float*)nullptr, (const float*)nullptr,
                               (float*)nullptr, N);
        }
        if (r == 0) {
            // x = LN(tanh(sc + x)); refresh fp32 sc for next block
            hipLaunchKernelGGL(tanh_ln_kernel, dim3(rgrid), dim3(256), 0, stream,
                               XB, B5, rlg, rlb, XB, B5,
                               (const float*)nullptr, (const float*)nullptr,
                               (float*)nullptr, N);
        } else {
            // final res-LN fused with classifier -> d_out
            hipLaunchKernelGGL(tanh_ln_kernel, dim3(rgrid), dim3(256), 0, stream,
                               XB, B5, rlg + H, rlb + H, (short*)nullptr,
                               (float*)nullptr, cW, cb, (float*)d_out, N);
        }
    }
}